// Round 3
// baseline (18429.358 us; speedup 1.0000x reference)
//
#include <hip/hip_runtime.h>
#include <hip/hip_bf16.h>

// Shapes (fixed by the reference)
#define BB 2
#define HH 256
#define WWID 256
#define CC 96
#define NHEADS 6
#define WSZ 8
#define SHIFTV 4
#define HDIM 16
#define NTOK 64
#define HID 192
#define LL 65536   // H*W

using bf16 = __hip_bfloat16;

__device__ __forceinline__ float b2f(bf16 v){ return __bfloat162float(v); }
__device__ __forceinline__ bf16  f2b(float f){ return __float2bfloat16(f); }
__device__ __forceinline__ float blo(unsigned u){ union {unsigned x; float f;} c; c.x = u << 16; return c.f; }
__device__ __forceinline__ float bhi(unsigned u){ union {unsigned x; float f;} c; c.x = u & 0xffff0000u; return c.f; }

__device__ __forceinline__ float dot8(uint4 a, uint4 b, float acc){
  acc += blo(a.x)*blo(b.x); acc += bhi(a.x)*bhi(b.x);
  acc += blo(a.y)*blo(b.y); acc += bhi(a.y)*bhi(b.y);
  acc += blo(a.z)*blo(b.z); acc += bhi(a.z)*bhi(b.z);
  acc += blo(a.w)*blo(b.w); acc += bhi(a.w)*bhi(b.w);
  return acc;
}

// ---------------- input dtype detection -------------------------------------
// bf16 data: low 16 bits of each dword are a bf16 of ~N(0,1) -> exponent in
// [118,130] ~99%. fp32 data: low 16 bits are mantissa bits -> ~5%. flag=1: fp32.
__global__ void detect_kernel(const unsigned* __restrict__ x, int* __restrict__ flag){
  __shared__ int s[256];
  int t = threadIdx.x;
  int cnt = 0;
  #pragma unroll
  for (int i = 0; i < 4; ++i){
    unsigned u = x[t*4 + i];
    unsigned e = (u >> 7) & 0xFFu;
    cnt += (e >= 118u && e <= 130u) ? 1 : 0;
  }
  s[t] = cnt; __syncthreads();
  for (int m = 128; m > 0; m >>= 1){ if (t < m) s[t] += s[t+m]; __syncthreads(); }
  if (t == 0) *flag = (s[0] < 512) ? 1 : 0;
}

// ---------------- convert all inputs into one packed bf16 block -------------
struct CvtArgs { const void* src[21]; long cum[22]; };

__global__ void cvt_kernel(CvtArgs a, const int* __restrict__ flag,
                           bf16* __restrict__ dst, long total){
  long k = (long)blockIdx.x * 256 + threadIdx.x;
  if (k >= total) return;
  int lo = 0;
  #pragma unroll
  for (int i = 0; i < 21; ++i) if (k >= a.cum[i+1]) lo = i+1;
  long e = k - a.cum[lo];
  if (*flag) dst[k] = f2b(((const float*)a.src[lo])[e]);
  else       dst[k] = ((const bf16*)a.src[lo])[e];
}

// ---------------- LayerNorm1 on x and ref (bf16 in -> bf16 out) -------------
__global__ __launch_bounds__(256) void ln1_kernel(const bf16* __restrict__ x, const bf16* __restrict__ ref,
                                                  const bf16* __restrict__ g, const bf16* __restrict__ bt,
                                                  bf16* __restrict__ xn, bf16* __restrict__ rn)
{
  int wave = threadIdx.x >> 6, lane = threadIdx.x & 63;
  long row = (long)blockIdx.x * 4 + wave;         // 0 .. 2*BB*LL-1
  const bf16* src; bf16* dst; long r;
  if (row < (long)BB*LL){ src = x; dst = xn; r = row; }
  else                  { src = ref; dst = rn; r = row - (long)BB*LL; }
  const bf16* p = src + r*CC;
  float v0 = b2f(p[lane]);
  float v1 = (lane < 32) ? b2f(p[64+lane]) : 0.f;
  float s = v0 + v1;
  #pragma unroll
  for (int m = 32; m >= 1; m >>= 1) s += __shfl_xor(s, m, 64);
  float mu = s * (1.f/CC);
  float d0 = v0 - mu, d1 = v1 - mu;
  float ss = d0*d0 + ((lane < 32) ? d1*d1 : 0.f);
  #pragma unroll
  for (int m = 32; m >= 1; m >>= 1) ss += __shfl_xor(ss, m, 64);
  float rstd = rsqrtf(ss * (1.f/CC) + 1e-5f);
  bf16* q = dst + r*CC;
  q[lane] = f2b(d0 * rstd * b2f(g[lane]) + b2f(bt[lane]));
  if (lane < 32) q[64+lane] = f2b(d1 * rstd * b2f(g[64+lane]) + b2f(bt[64+lane]));
}

// ---------------- LayerNorm2 (bf16 in -> bf16 out) --------------------------
__global__ __launch_bounds__(256) void ln2_kernel(const bf16* __restrict__ xin,
                                                  const bf16* __restrict__ g, const bf16* __restrict__ bt,
                                                  bf16* __restrict__ out)
{
  int wave = threadIdx.x >> 6, lane = threadIdx.x & 63;
  long r = (long)blockIdx.x * 4 + wave;           // 0 .. BB*LL-1
  const bf16* p = xin + r*CC;
  float v0 = b2f(p[lane]);
  float v1 = (lane < 32) ? b2f(p[64+lane]) : 0.f;
  float s = v0 + v1;
  #pragma unroll
  for (int m = 32; m >= 1; m >>= 1) s += __shfl_xor(s, m, 64);
  float mu = s * (1.f/CC);
  float d0 = v0 - mu, d1 = v1 - mu;
  float ss = d0*d0 + ((lane < 32) ? d1*d1 : 0.f);
  #pragma unroll
  for (int m = 32; m >= 1; m >>= 1) ss += __shfl_xor(ss, m, 64);
  float rstd = rsqrtf(ss * (1.f/CC) + 1e-5f);
  bf16* q = out + r*CC;
  q[lane] = f2b(d0 * rstd * b2f(g[lane]) + b2f(bt[lane]));
  if (lane < 32) q[64+lane] = f2b(d1 * rstd * b2f(g[64+lane]) + b2f(bt[64+lane]));
}

// ---------------- Fused window attention (both paths, gated) ----------------
__global__ __launch_bounds__(256) void attn_kernel(const bf16* __restrict__ xn, const bf16* __restrict__ rn,
                                                   const bf16* __restrict__ qkv_w, const bf16* __restrict__ qkv_b,
                                                   const bf16* __restrict__ lsc, const bf16* __restrict__ gat,
                                                   const bf16* __restrict__ rpbt, bf16* __restrict__ img)
{
  __shared__ __align__(16) bf16 sx[NTOK][CC];
  __shared__ __align__(16) bf16 sr[NTOK][CC];
  __shared__ __align__(16) bf16 wb[48][CC];
  __shared__ float sbias[48];
  __shared__ __align__(16) float qh[NTOK][HDIM];
  __shared__ float kh[NTOK][HDIM], vh[NTOK][HDIM], krh[NTOK][HDIM], vrh[NTOK][HDIM];

  int widx = blockIdx.x;
  int b  = widx >> 10;
  int wib = widx & 1023;
  int wh = wib >> 5, ww = wib & 31;
  int tid = threadIdx.x;

  for (int idx = tid; idx < NTOK*CC; idx += 256){
    int n = idx / CC, c = idx - n*CC;
    int i = n >> 3, j = n & 7;
    int h0 = (wh*8 + i + SHIFTV) & 255;
    int w0 = (ww*8 + j + SHIFTV) & 255;
    long base = (((long)b*HH + h0)*WWID + w0)*CC + c;
    sx[n][c] = xn[base];
    sr[n][c] = rn[base];
  }
  __syncthreads();

  int n  = tid >> 2;
  int qq = tid & 3;
  int i1 = n >> 3, j1 = n & 7;
  int rl1 = (wh < 31) ? 0 : (i1 < 4 ? 1 : 2);
  int cl1 = (ww < 31) ? 0 : (j1 < 4 ? 1 : 2);
  int reg1 = rl1*3 + cl1;

  for (int h = 0; h < NHEADS; ++h){
    for (int idx = tid; idx < 48*CC; idx += 256){
      int rr = idx / CC, c = idx - rr*CC;
      int o = (rr >> 4)*CC + h*HDIM + (rr & 15);
      wb[rr][c] = qkv_w[(long)o*CC + c];
    }
    if (tid < 48){
      int o = (tid >> 4)*CC + h*HDIM + (tid & 15);
      sbias[tid] = b2f(qkv_b[o]);
    }
    __syncthreads();

    for (int idx = tid; idx < 5*NTOK*HDIM; idx += 256){
      int which = idx >> 10;
      int rem = idx & 1023;
      int nn = rem >> 4, d = rem & 15;
      int wrow = (which == 0) ? d : (which == 1 || which == 3) ? 16 + d : 32 + d;
      const bf16* srow = (which < 3) ? sx[nn] : sr[nn];
      const uint4* a = (const uint4*)srow;
      const uint4* wv = (const uint4*)wb[wrow];
      float acc = sbias[wrow];
      #pragma unroll
      for (int kk = 0; kk < 12; ++kk) acc = dot8(a[kk], wv[kk], acc);
      float* dstf = (which==0) ? &qh[0][0] : (which==1) ? &kh[0][0] : (which==2) ? &vh[0][0]
                    : (which==3) ? &krh[0][0] : &vrh[0][0];
      dstf[(nn << 4) + d] = acc;
    }
    __syncthreads();

    if (tid < 192){
      int rr = tid & 63;
      float* row = (tid < 64) ? qh[rr] : (tid < 128) ? kh[rr] : krh[rr];
      float s = 0.f;
      #pragma unroll
      for (int d = 0; d < 16; ++d) s += row[d]*row[d];
      float inv = 1.f / fmaxf(sqrtf(s), 1e-12f);
      #pragma unroll
      for (int d = 0; d < 16; ++d) row[d] *= inv;
    }
    __syncthreads();

    float ls = expf(fminf(b2f(lsc[h]), 4.605170185988091f));
    float gv = b2f(gat[h]);
    float g = 1.f / (1.f + expf(-gv));

    float qr[16];
    #pragma unroll
    for (int d = 0; d < 16; ++d) qr[d] = qh[n][d];

    float s1[16], s2[16];
    #pragma unroll
    for (int u = 0; u < 16; ++u){
      int m = qq*16 + u;
      float a1 = 0.f, a2 = 0.f;
      #pragma unroll
      for (int d = 0; d < 16; ++d){ a1 += qr[d]*kh[m][d]; a2 += qr[d]*krh[m][d]; }
      int i2 = m >> 3, j2 = m & 7;
      float rp = b2f(rpbt[((i1 - i2 + 7)*15 + (j1 - j2 + 7))*NHEADS + h]);
      int rl2 = (wh < 31) ? 0 : (i2 < 4 ? 1 : 2);
      int cl2 = (ww < 31) ? 0 : (j2 < 4 ? 1 : 2);
      float msk = (reg1 != rl2*3 + cl2) ? -100.f : 0.f;
      s1[u] = a1*ls + rp + msk;
      s2[u] = a2*ls + rp + msk;
    }
    float mx1 = -1e30f, mx2 = -1e30f;
    #pragma unroll
    for (int u = 0; u < 16; ++u){ mx1 = fmaxf(mx1, s1[u]); mx2 = fmaxf(mx2, s2[u]); }
    #pragma unroll
    for (int m = 1; m < 4; m <<= 1){ mx1 = fmaxf(mx1, __shfl_xor(mx1, m, 64)); mx2 = fmaxf(mx2, __shfl_xor(mx2, m, 64)); }
    float sm1 = 0.f, sm2 = 0.f;
    #pragma unroll
    for (int u = 0; u < 16; ++u){ s1[u] = expf(s1[u]-mx1); sm1 += s1[u]; s2[u] = expf(s2[u]-mx2); sm2 += s2[u]; }
    #pragma unroll
    for (int m = 1; m < 4; m <<= 1){ sm1 += __shfl_xor(sm1, m, 64); sm2 += __shfl_xor(sm2, m, 64); }
    float p1s = (1.f - g) / sm1, p2s = g / sm2;

    float po[16];
    #pragma unroll
    for (int d = 0; d < 16; ++d) po[d] = 0.f;
    #pragma unroll
    for (int u = 0; u < 16; ++u){
      int m = qq*16 + u;
      float p1 = s1[u]*p1s, p2 = s2[u]*p2s;
      #pragma unroll
      for (int d = 0; d < 16; ++d) po[d] += p1*vh[m][d] + p2*vrh[m][d];
    }
    #pragma unroll
    for (int m = 1; m < 4; m <<= 1){
      #pragma unroll
      for (int d = 0; d < 16; ++d) po[d] += __shfl_xor(po[d], m, 64);
    }
    {
      int hs = wh*8 + i1, wsp = ww*8 + j1;
      long obase = (((long)b*HH + hs)*WWID + wsp)*CC + h*HDIM + qq*4;
      #pragma unroll
      for (int d = 0; d < 4; ++d) img[obase + d] = f2b(po[qq*4 + d]);
    }
    __syncthreads();
  }
}

// ---------------- 3x3 conv, 96->96, direct, P=4 pixels/thread ---------------
__global__ __launch_bounds__(256) void conv96_kernel(const bf16* __restrict__ src, const bf16* __restrict__ w,
                                                     const bf16* __restrict__ bias, const bf16* __restrict__ base,
                                                     bf16* __restrict__ dst, int relu_mode)
{
  __shared__ __align__(16) bf16 tile[10*18*CC];
  __shared__ __align__(16) float wt[48*CC];
  int tx0 = blockIdx.x * 16, ty0 = blockIdx.y * 8, bb = blockIdx.z;
  int tid = threadIdx.x;
  for (int idx = tid; idx < 10*18*CC; idx += 256){
    int yy = idx / (18*CC); int rem = idx - yy*(18*CC);
    int xx = rem / CC; int ci = rem - xx*CC;
    int gy = ty0 + yy - 1, gx = tx0 + xx - 1;
    bf16 v = f2b(0.f);
    if (gy >= 0 && gy < HH && gx >= 0 && gx < WWID)
      v = src[(((long)bb*HH + gy)*WWID + gx)*CC + ci];
    tile[idx] = v;
  }
  int pg = tid >> 3, cg = tid & 7;
  int py = pg >> 2, px0 = (pg & 3) * 4;
  int co0 = cg * 12;
  float acc[4][12];
  #pragma unroll
  for (int k = 0; k < 4; ++k)
    #pragma unroll
    for (int u = 0; u < 12; ++u) acc[k][u] = b2f(bias[co0 + u]);
  for (int tap = 0; tap < 9; ++tap){
    int dy = tap / 3, dx = tap - dy*3;
    for (int cc = 0; cc < 2; ++cc){
      __syncthreads();
      for (int idx = tid; idx < 48*CC; idx += 256){
        int rr = idx / CC, c = idx - rr*CC;
        wt[idx] = b2f(w[(long)tap*CC*CC + (long)(cc*48 + rr)*CC + c]);
      }
      __syncthreads();
      const bf16* trow = &tile[((py+dy)*18 + (px0+dx))*CC + cc*48];
      for (int ci = 0; ci < 48; ++ci){
        float a0 = b2f(trow[ci]);
        float a1 = b2f(trow[ci + CC]);
        float a2 = b2f(trow[ci + 2*CC]);
        float a3 = b2f(trow[ci + 3*CC]);
        const float* wr = &wt[ci*CC + co0];
        #pragma unroll
        for (int u = 0; u < 12; ++u){
          float wv = wr[u];
          acc[0][u] += a0*wv; acc[1][u] += a1*wv; acc[2][u] += a2*wv; acc[3][u] += a3*wv;
        }
      }
    }
  }
  #pragma unroll
  for (int k = 0; k < 4; ++k){
    long obase = (((long)bb*HH + ty0+py)*WWID + tx0+px0+k)*CC + co0;
    if (relu_mode){
      #pragma unroll
      for (int u = 0; u < 12; ++u) dst[obase+u] = f2b(fmaxf(acc[k][u], 0.f));
    } else {
      #pragma unroll
      for (int u = 0; u < 12; ++u) dst[obase+u] = f2b(b2f(base[obase+u]) + acc[k][u]);
    }
  }
}

// ---------------- 3x3 conv, 192->192, + exact GELU --------------------------
__global__ __launch_bounds__(256) void convm_kernel(const bf16* __restrict__ src, const bf16* __restrict__ w,
                                                    const bf16* __restrict__ bias, bf16* __restrict__ dst)
{
  __shared__ __align__(16) bf16 tile[10*10*HID];
  __shared__ __align__(16) float wt[32*HID];
  int tx0 = blockIdx.x * 8, ty0 = blockIdx.y * 8, bb = blockIdx.z;
  int tid = threadIdx.x;
  for (int idx = tid; idx < 10*10*HID; idx += 256){
    int yy = idx / (10*HID); int rem = idx - yy*(10*HID);
    int xx = rem / HID; int ci = rem - xx*HID;
    int gy = ty0 + yy - 1, gx = tx0 + xx - 1;
    bf16 v = f2b(0.f);
    if (gy >= 0 && gy < HH && gx >= 0 && gx < WWID)
      v = src[(((long)bb*HH + gy)*WWID + gx)*HID + ci];
    tile[idx] = v;
  }
  int pg = tid >> 4, cg = tid & 15;
  int py = pg >> 1, px0 = (pg & 1) * 4;
  int co0 = cg * 12;
  float acc[4][12];
  #pragma unroll
  for (int k = 0; k < 4; ++k)
    #pragma unroll
    for (int u = 0; u < 12; ++u) acc[k][u] = b2f(bias[co0 + u]);
  for (int tap = 0; tap < 9; ++tap){
    int dy = tap / 3, dx = tap - dy*3;
    for (int cc = 0; cc < 6; ++cc){
      __syncthreads();
      for (int idx = tid; idx < 32*HID; idx += 256){
        int rr = idx / HID, c = idx - rr*HID;
        wt[idx] = b2f(w[(long)tap*HID*HID + (long)(cc*32 + rr)*HID + c]);
      }
      __syncthreads();
      const bf16* trow = &tile[((py+dy)*10 + (px0+dx))*HID + cc*32];
      for (int ci = 0; ci < 32; ++ci){
        float a0 = b2f(trow[ci]);
        float a1 = b2f(trow[ci + HID]);
        float a2 = b2f(trow[ci + 2*HID]);
        float a3 = b2f(trow[ci + 3*HID]);
        const float* wr = &wt[ci*HID + co0];
        #pragma unroll
        for (int u = 0; u < 12; ++u){
          float wv = wr[u];
          acc[0][u] += a0*wv; acc[1][u] += a1*wv; acc[2][u] += a2*wv; acc[3][u] += a3*wv;
        }
      }
    }
  }
  #pragma unroll
  for (int k = 0; k < 4; ++k){
    long obase = (((long)bb*HH + ty0+py)*WWID + tx0+px0+k)*HID + co0;
    #pragma unroll
    for (int u = 0; u < 12; ++u){
      float v = acc[k][u];
      dst[obase+u] = f2b(0.5f * v * (1.f + erff(v * 0.7071067811865476f)));
    }
  }
}

// ---------------- proj (96x96) + roll-back(+4,+4) + shortcut -> bf16 xmid ---
__global__ __launch_bounds__(256) void proj_kernel(const bf16* __restrict__ img, const bf16* __restrict__ pw,
                                                   const bf16* __restrict__ pb, const bf16* __restrict__ xorig,
                                                   bf16* __restrict__ xmid)
{
  __shared__ __align__(16) bf16 rows[64][CC];
  __shared__ __align__(16) bf16 wsm[CC][CC];
  long pix0 = (long)blockIdx.x * 64;
  int tid = threadIdx.x;
  for (int idx = tid; idx < 64*CC; idx += 256){
    int pp = idx / CC, c = idx - pp*CC;
    long pix = pix0 + pp;
    int b = (int)(pix >> 16); int hw = (int)(pix & 65535);
    int h = hw >> 8, wc = hw & 255;
    int sh = (h - SHIFTV) & 255, sw = (wc - SHIFTV) & 255;
    rows[pp][c] = img[(((long)b*HH + sh)*WWID + sw)*CC + c];
  }
  for (int idx = tid; idx < CC*CC; idx += 256) (&wsm[0][0])[idx] = pw[idx];
  __syncthreads();
  int ty = tid >> 4, tx = tid & 15;
  int r0 = ty*4, c0 = tx*6;
  float acc[4][6];
  #pragma unroll
  for (int i = 0; i < 4; ++i)
    #pragma unroll
    for (int j = 0; j < 6; ++j) acc[i][j] = b2f(pb[c0+j]);
  #pragma unroll
  for (int kk = 0; kk < 12; ++kk){
    uint4 a[4], wv[6];
    #pragma unroll
    for (int i = 0; i < 4; ++i) a[i] = ((const uint4*)rows[r0+i])[kk];
    #pragma unroll
    for (int j = 0; j < 6; ++j) wv[j] = ((const uint4*)wsm[c0+j])[kk];
    #pragma unroll
    for (int i = 0; i < 4; ++i)
      #pragma unroll
      for (int j = 0; j < 6; ++j) acc[i][j] = dot8(a[i], wv[j], acc[i][j]);
  }
  #pragma unroll
  for (int i = 0; i < 4; ++i){
    long pix = pix0 + r0 + i;
    #pragma unroll
    for (int j = 0; j < 6; ++j){
      long oi = pix*CC + c0 + j;
      xmid[oi] = f2b(b2f(xorig[oi]) + acc[i][j]);
    }
  }
}

// ---------------- fc1: 96->192 + exact GELU ---------------------------------
__global__ __launch_bounds__(256) void fc1_kernel(const bf16* __restrict__ src, const bf16* __restrict__ w,
                                                  const bf16* __restrict__ bias, bf16* __restrict__ dst)
{
  __shared__ __align__(16) bf16 rows[64][CC];
  __shared__ __align__(16) bf16 wsm[HID][CC];
  long pix0 = (long)blockIdx.x * 64;
  int tid = threadIdx.x;
  for (int idx = tid; idx < 64*CC; idx += 256){
    int pp = idx / CC, c = idx - pp*CC;
    rows[pp][c] = src[(pix0 + pp)*CC + c];
  }
  for (int idx = tid; idx < HID*CC; idx += 256) (&wsm[0][0])[idx] = w[idx];
  __syncthreads();
  int ty = tid >> 4, tx = tid & 15;
  int r0 = ty*4, c0 = tx*12;
  float acc[4][12];
  #pragma unroll
  for (int i = 0; i < 4; ++i)
    #pragma unroll
    for (int j = 0; j < 12; ++j) acc[i][j] = b2f(bias[c0+j]);
  #pragma unroll
  for (int kk = 0; kk < 12; ++kk){
    uint4 a[4];
    #pragma unroll
    for (int i = 0; i < 4; ++i) a[i] = ((const uint4*)rows[r0+i])[kk];
    #pragma unroll
    for (int j = 0; j < 12; ++j){
      uint4 wv = ((const uint4*)wsm[c0+j])[kk];
      #pragma unroll
      for (int i = 0; i < 4; ++i) acc[i][j] = dot8(a[i], wv, acc[i][j]);
    }
  }
  #pragma unroll
  for (int i = 0; i < 4; ++i){
    long pix = pix0 + r0 + i;
    #pragma unroll
    for (int j = 0; j < 12; ++j){
      float v = acc[i][j];
      dst[pix*HID + c0 + j] = f2b(0.5f * v * (1.f + erff(v * 0.7071067811865476f)));
    }
  }
}

// ---------------- fc2: 192->96 + bf16 xmid residual -> out (flag dtype) -----
__global__ __launch_bounds__(256) void fc2_kernel(const bf16* __restrict__ src, const bf16* __restrict__ w,
                                                  const bf16* __restrict__ bias, const bf16* __restrict__ xmid,
                                                  void* __restrict__ outv, const int* __restrict__ flag)
{
  __shared__ __align__(16) bf16 rows[64][HID];
  __shared__ __align__(16) bf16 wsm[CC][HID];
  long pix0 = (long)blockIdx.x * 64;
  int tid = threadIdx.x;
  for (int idx = tid; idx < 64*HID; idx += 256){
    int pp = idx / HID, c = idx - pp*HID;
    rows[pp][c] = src[(pix0 + pp)*HID + c];
  }
  for (int idx = tid; idx < CC*HID; idx += 256) (&wsm[0][0])[idx] = w[idx];
  __syncthreads();
  int ty = tid >> 4, tx = tid & 15;
  int r0 = ty*4, c0 = tx*6;
  float acc[4][6];
  #pragma unroll
  for (int i = 0; i < 4; ++i)
    #pragma unroll
    for (int j = 0; j < 6; ++j) acc[i][j] = b2f(bias[c0+j]);
  #pragma unroll
  for (int kk = 0; kk < 24; ++kk){
    uint4 a[4], wv[6];
    #pragma unroll
    for (int i = 0; i < 4; ++i) a[i] = ((const uint4*)rows[r0+i])[kk];
    #pragma unroll
    for (int j = 0; j < 6; ++j) wv[j] = ((const uint4*)wsm[c0+j])[kk];
    #pragma unroll
    for (int i = 0; i < 4; ++i)
      #pragma unroll
      for (int j = 0; j < 6; ++j) acc[i][j] = dot8(a[i], wv[j], acc[i][j]);
  }
  int f = *flag;
  #pragma unroll
  for (int i = 0; i < 4; ++i){
    long pix = pix0 + r0 + i;
    #pragma unroll
    for (int j = 0; j < 6; ++j){
      long oi = pix*CC + c0 + j;
      float v = b2f(xmid[oi]) + acc[i][j];
      if (f) ((float*)outv)[oi] = v;
      else   ((bf16*)outv)[oi] = f2b(v);
    }
  }
}

extern "C" void kernel_launch(void* const* d_in, const int* in_sizes, int n_in,
                              void* d_out, int out_size, void* d_ws, size_t ws_size,
                              hipStream_t stream)
{
  // --- packed bf16 input block -----------------------------------------------
  long cum[22]; cum[0] = 0;
  for (int i = 0; i < 21; ++i) cum[i+1] = cum[i] + in_sizes[i];
  long total = cum[21];

  CvtArgs a;
  for (int i = 0; i < 21; ++i) a.src[i] = d_in[i];
  for (int i = 0; i < 22; ++i) a.cum[i] = cum[i];

  char* ws = (char*)d_ws;
  int*  flag   = (int*)ws;
  bf16* packed = (bf16*)(ws + 1048576);           // [1MB, ~50.4MB)

  detect_kernel<<<1, 256, 0, stream>>>((const unsigned*)d_in[0], flag);
  cvt_kernel<<<(int)((total + 255) / 256), 256, 0, stream>>>(a, flag, packed, total);

  #define PP(i) (packed + cum[i])
  const bf16* xc    = PP(0);
  const bf16* rc    = PP(1);
  const bf16* n1g   = PP(2);
  const bf16* n1b   = PP(3);
  const bf16* qkv_w = PP(4);
  const bf16* qkv_b = PP(5);
  const bf16* lsc   = PP(6);
  const bf16* gat   = PP(7);
  const bf16* rpbt  = PP(8);
  const bf16* tw    = PP(9);
  const bf16* tb    = PP(10);
  const bf16* pw    = PP(11);
  const bf16* pb    = PP(12);
  const bf16* n2g   = PP(13);
  const bf16* n2b   = PP(14);
  const bf16* f1w   = PP(15);
  const bf16* f1b   = PP(16);
  const bf16* cmw   = PP(17);
  const bf16* cmb   = PP(18);
  const bf16* f2w   = PP(19);
  const bf16* f2bp  = PP(20);

  // --- workspace layout (peak 123 MB) ---------------------------------------
  bf16* xn   = (bf16*)(ws + 53477376);            // 51 MB
  bf16* rn   = (bf16*)(ws + 78643200);            // 75 MB
  bf16* img  = (bf16*)(ws + 103809024);           // 99 MB
  bf16* rtr  = xn;                                // trunk scratch (xn dead after attn)
  bf16* xmid = xn;                                // proj out (rtr dead after trunk)
  bf16* ln2o = rn;                                // LN2 out (rn dead after attn)
  bf16* h1   = (bf16*)(ws + 1048576);             // [1,49)MB (xc/rc dead by fc1)
  bf16* hc   = rn;                                // [75,123)MB (ln2o+img dead by convm)

  ln1_kernel<<<65536, 256, 0, stream>>>(xc, rc, n1g, n1b, xn, rn);
  attn_kernel<<<2048, 256, 0, stream>>>(xn, rn, qkv_w, qkv_b, lsc, gat, rpbt, img);

  conv96_kernel<<<dim3(16,32,2), 256, 0, stream>>>(img, tw + 0*82944, tb + 0,   nullptr, rtr, 1);
  conv96_kernel<<<dim3(16,32,2), 256, 0, stream>>>(rtr, tw + 1*82944, tb + 96,  img,     img, 0);
  conv96_kernel<<<dim3(16,32,2), 256, 0, stream>>>(img, tw + 2*82944, tb + 192, nullptr, rtr, 1);
  conv96_kernel<<<dim3(16,32,2), 256, 0, stream>>>(rtr, tw + 3*82944, tb + 288, img,     img, 0);

  proj_kernel<<<2048, 256, 0, stream>>>(img, pw, pb, xc, xmid);
  ln2_kernel<<<32768, 256, 0, stream>>>(xmid, n2g, n2b, ln2o);
  fc1_kernel<<<2048, 256, 0, stream>>>(ln2o, f1w, f1b, h1);
  convm_kernel<<<dim3(32,32,2), 256, 0, stream>>>(h1, cmw, cmb, hc);
  fc2_kernel<<<2048, 256, 0, stream>>>(hc, f2w, f2bp, xmid, d_out, flag);
}

// Round 4
// 4289.223 us; speedup vs baseline: 4.2967x; 4.2967x over previous
//
#include <hip/hip_runtime.h>
#include <hip/hip_bf16.h>

// Shapes (fixed by the reference)
#define BB 2
#define HH 256
#define WWID 256
#define CC 96
#define NHEADS 6
#define WSZ 8
#define SHIFTV 4
#define HDIM 16
#define NTOK 64
#define HID 192
#define LL 65536   // H*W

using bf16 = __hip_bfloat16;

__device__ __forceinline__ float b2f(bf16 v){ return __bfloat162float(v); }
__device__ __forceinline__ bf16  f2b(float f){ return __float2bfloat16(f); }
__device__ __forceinline__ float blo(unsigned u){ union {unsigned x; float f;} c; c.x = u << 16; return c.f; }
__device__ __forceinline__ float bhi(unsigned u){ union {unsigned x; float f;} c; c.x = u & 0xffff0000u; return c.f; }

__device__ __forceinline__ float dot8(uint4 a, uint4 b, float acc){
  acc += blo(a.x)*blo(b.x); acc += bhi(a.x)*bhi(b.x);
  acc += blo(a.y)*blo(b.y); acc += bhi(a.y)*bhi(b.y);
  acc += blo(a.z)*blo(b.z); acc += bhi(a.z)*bhi(b.z);
  acc += blo(a.w)*blo(b.w); acc += bhi(a.w)*bhi(b.w);
  return acc;
}

// ---------------- input dtype detection -------------------------------------
__global__ void detect_kernel(const unsigned* __restrict__ x, int* __restrict__ flag){
  __shared__ int s[256];
  int t = threadIdx.x;
  int cnt = 0;
  #pragma unroll
  for (int i = 0; i < 4; ++i){
    unsigned u = x[t*4 + i];
    unsigned e = (u >> 7) & 0xFFu;
    cnt += (e >= 118u && e <= 130u) ? 1 : 0;
  }
  s[t] = cnt; __syncthreads();
  for (int m = 128; m > 0; m >>= 1){ if (t < m) s[t] += s[t+m]; __syncthreads(); }
  if (t == 0) *flag = (s[0] < 512) ? 1 : 0;
}

// ---------------- convert all inputs into one packed bf16 block -------------
struct CvtArgs { const void* src[21]; long cum[22]; };

__global__ void cvt_kernel(CvtArgs a, const int* __restrict__ flag,
                           bf16* __restrict__ dst, long total){
  long k = (long)blockIdx.x * 256 + threadIdx.x;
  if (k >= total) return;
  int lo = 0;
  #pragma unroll
  for (int i = 0; i < 21; ++i) if (k >= a.cum[i+1]) lo = i+1;
  long e = k - a.cum[lo];
  if (*flag) dst[k] = f2b(((const float*)a.src[lo])[e]);
  else       dst[k] = ((const bf16*)a.src[lo])[e];
}

// ---------------- LayerNorm1 on x and ref (bf16 in -> bf16 out) -------------
__global__ __launch_bounds__(256) void ln1_kernel(const bf16* __restrict__ x, const bf16* __restrict__ ref,
                                                  const bf16* __restrict__ g, const bf16* __restrict__ bt,
                                                  bf16* __restrict__ xn, bf16* __restrict__ rn)
{
  int wave = threadIdx.x >> 6, lane = threadIdx.x & 63;
  long row = (long)blockIdx.x * 4 + wave;         // 0 .. 2*BB*LL-1
  const bf16* src; bf16* dst; long r;
  if (row < (long)BB*LL){ src = x; dst = xn; r = row; }
  else                  { src = ref; dst = rn; r = row - (long)BB*LL; }
  const bf16* p = src + r*CC;
  float v0 = b2f(p[lane]);
  float v1 = (lane < 32) ? b2f(p[64+lane]) : 0.f;
  float s = v0 + v1;
  #pragma unroll
  for (int m = 32; m >= 1; m >>= 1) s += __shfl_xor(s, m, 64);
  float mu = s * (1.f/CC);
  float d0 = v0 - mu, d1 = v1 - mu;
  float ss = d0*d0 + ((lane < 32) ? d1*d1 : 0.f);
  #pragma unroll
  for (int m = 32; m >= 1; m >>= 1) ss += __shfl_xor(ss, m, 64);
  float rstd = rsqrtf(ss * (1.f/CC) + 1e-5f);
  bf16* q = dst + r*CC;
  q[lane] = f2b(d0 * rstd * b2f(g[lane]) + b2f(bt[lane]));
  if (lane < 32) q[64+lane] = f2b(d1 * rstd * b2f(g[64+lane]) + b2f(bt[64+lane]));
}

// ---------------- LayerNorm2 (bf16 in -> bf16 out) --------------------------
__global__ __launch_bounds__(256) void ln2_kernel(const bf16* __restrict__ xin,
                                                  const bf16* __restrict__ g, const bf16* __restrict__ bt,
                                                  bf16* __restrict__ out)
{
  int wave = threadIdx.x >> 6, lane = threadIdx.x & 63;
  long r = (long)blockIdx.x * 4 + wave;           // 0 .. BB*LL-1
  const bf16* p = xin + r*CC;
  float v0 = b2f(p[lane]);
  float v1 = (lane < 32) ? b2f(p[64+lane]) : 0.f;
  float s = v0 + v1;
  #pragma unroll
  for (int m = 32; m >= 1; m >>= 1) s += __shfl_xor(s, m, 64);
  float mu = s * (1.f/CC);
  float d0 = v0 - mu, d1 = v1 - mu;
  float ss = d0*d0 + ((lane < 32) ? d1*d1 : 0.f);
  #pragma unroll
  for (int m = 32; m >= 1; m >>= 1) ss += __shfl_xor(ss, m, 64);
  float rstd = rsqrtf(ss * (1.f/CC) + 1e-5f);
  bf16* q = out + r*CC;
  q[lane] = f2b(d0 * rstd * b2f(g[lane]) + b2f(bt[lane]));
  if (lane < 32) q[64+lane] = f2b(d1 * rstd * b2f(g[64+lane]) + b2f(bt[64+lane]));
}

// ---------------- Fused window attention (both paths, gated) ----------------
__global__ __launch_bounds__(256) void attn_kernel(const bf16* __restrict__ xn, const bf16* __restrict__ rn,
                                                   const bf16* __restrict__ qkv_w, const bf16* __restrict__ qkv_b,
                                                   const bf16* __restrict__ lsc, const bf16* __restrict__ gat,
                                                   const bf16* __restrict__ rpbt, bf16* __restrict__ img)
{
  __shared__ __align__(16) bf16 sx[NTOK][CC];
  __shared__ __align__(16) bf16 sr[NTOK][CC];
  __shared__ __align__(16) bf16 wb[48][CC];
  __shared__ float sbias[48];
  __shared__ __align__(16) float qh[NTOK][HDIM];
  __shared__ float kh[NTOK][HDIM], vh[NTOK][HDIM], krh[NTOK][HDIM], vrh[NTOK][HDIM];

  int widx = blockIdx.x;
  int b  = widx >> 10;
  int wib = widx & 1023;
  int wh = wib >> 5, ww = wib & 31;
  int tid = threadIdx.x;

  for (int idx = tid; idx < NTOK*CC; idx += 256){
    int n = idx / CC, c = idx - n*CC;
    int i = n >> 3, j = n & 7;
    int h0 = (wh*8 + i + SHIFTV) & 255;
    int w0 = (ww*8 + j + SHIFTV) & 255;
    long base = (((long)b*HH + h0)*WWID + w0)*CC + c;
    sx[n][c] = xn[base];
    sr[n][c] = rn[base];
  }
  __syncthreads();

  int n  = tid >> 2;
  int qq = tid & 3;
  int i1 = n >> 3, j1 = n & 7;
  int rl1 = (wh < 31) ? 0 : (i1 < 4 ? 1 : 2);
  int cl1 = (ww < 31) ? 0 : (j1 < 4 ? 1 : 2);
  int reg1 = rl1*3 + cl1;

  for (int h = 0; h < NHEADS; ++h){
    for (int idx = tid; idx < 48*CC; idx += 256){
      int rr = idx / CC, c = idx - rr*CC;
      int o = (rr >> 4)*CC + h*HDIM + (rr & 15);
      wb[rr][c] = qkv_w[(long)o*CC + c];
    }
    if (tid < 48){
      int o = (tid >> 4)*CC + h*HDIM + (tid & 15);
      sbias[tid] = b2f(qkv_b[o]);
    }
    __syncthreads();

    for (int idx = tid; idx < 5*NTOK*HDIM; idx += 256){
      int which = idx >> 10;
      int rem = idx & 1023;
      int nn = rem >> 4, d = rem & 15;
      int wrow = (which == 0) ? d : (which == 1 || which == 3) ? 16 + d : 32 + d;
      const bf16* srow = (which < 3) ? sx[nn] : sr[nn];
      const uint4* a = (const uint4*)srow;
      const uint4* wv = (const uint4*)wb[wrow];
      float acc = sbias[wrow];
      #pragma unroll
      for (int kk = 0; kk < 12; ++kk) acc = dot8(a[kk], wv[kk], acc);
      float* dstf = (which==0) ? &qh[0][0] : (which==1) ? &kh[0][0] : (which==2) ? &vh[0][0]
                    : (which==3) ? &krh[0][0] : &vrh[0][0];
      dstf[(nn << 4) + d] = acc;
    }
    __syncthreads();

    if (tid < 192){
      int rr = tid & 63;
      float* row = (tid < 64) ? qh[rr] : (tid < 128) ? kh[rr] : krh[rr];
      float s = 0.f;
      #pragma unroll
      for (int d = 0; d < 16; ++d) s += row[d]*row[d];
      float inv = 1.f / fmaxf(sqrtf(s), 1e-12f);
      #pragma unroll
      for (int d = 0; d < 16; ++d) row[d] *= inv;
    }
    __syncthreads();

    float ls = expf(fminf(b2f(lsc[h]), 4.605170185988091f));
    float gv = b2f(gat[h]);
    float g = 1.f / (1.f + expf(-gv));

    float qr[16];
    #pragma unroll
    for (int d = 0; d < 16; ++d) qr[d] = qh[n][d];

    float s1[16], s2[16];
    #pragma unroll
    for (int u = 0; u < 16; ++u){
      int m = qq*16 + u;
      float a1 = 0.f, a2 = 0.f;
      #pragma unroll
      for (int d = 0; d < 16; ++d){ a1 += qr[d]*kh[m][d]; a2 += qr[d]*krh[m][d]; }
      int i2 = m >> 3, j2 = m & 7;
      float rp = b2f(rpbt[((i1 - i2 + 7)*15 + (j1 - j2 + 7))*NHEADS + h]);
      int rl2 = (wh < 31) ? 0 : (i2 < 4 ? 1 : 2);
      int cl2 = (ww < 31) ? 0 : (j2 < 4 ? 1 : 2);
      float msk = (reg1 != rl2*3 + cl2) ? -100.f : 0.f;
      s1[u] = a1*ls + rp + msk;
      s2[u] = a2*ls + rp + msk;
    }
    float mx1 = -1e30f, mx2 = -1e30f;
    #pragma unroll
    for (int u = 0; u < 16; ++u){ mx1 = fmaxf(mx1, s1[u]); mx2 = fmaxf(mx2, s2[u]); }
    #pragma unroll
    for (int m = 1; m < 4; m <<= 1){ mx1 = fmaxf(mx1, __shfl_xor(mx1, m, 64)); mx2 = fmaxf(mx2, __shfl_xor(mx2, m, 64)); }
    float sm1 = 0.f, sm2 = 0.f;
    #pragma unroll
    for (int u = 0; u < 16; ++u){ s1[u] = expf(s1[u]-mx1); sm1 += s1[u]; s2[u] = expf(s2[u]-mx2); sm2 += s2[u]; }
    #pragma unroll
    for (int m = 1; m < 4; m <<= 1){ sm1 += __shfl_xor(sm1, m, 64); sm2 += __shfl_xor(sm2, m, 64); }
    float p1s = (1.f - g) / sm1, p2s = g / sm2;

    float po[16];
    #pragma unroll
    for (int d = 0; d < 16; ++d) po[d] = 0.f;
    #pragma unroll
    for (int u = 0; u < 16; ++u){
      int m = qq*16 + u;
      float p1 = s1[u]*p1s, p2 = s2[u]*p2s;
      #pragma unroll
      for (int d = 0; d < 16; ++d) po[d] += p1*vh[m][d] + p2*vrh[m][d];
    }
    #pragma unroll
    for (int m = 1; m < 4; m <<= 1){
      #pragma unroll
      for (int d = 0; d < 16; ++d) po[d] += __shfl_xor(po[d], m, 64);
    }
    {
      int hs = wh*8 + i1, wsp = ww*8 + j1;
      long obase = (((long)b*HH + hs)*WWID + wsp)*CC + h*HDIM + qq*4;
      #pragma unroll
      for (int d = 0; d < 4; ++d) img[obase + d] = f2b(po[qq*4 + d]);
    }
    __syncthreads();
  }
}

// ---------------- 3x3 conv, 96->96, direct, P=4 pixels/thread ---------------
__global__ __launch_bounds__(256) void conv96_kernel(const bf16* __restrict__ src, const bf16* __restrict__ w,
                                                     const bf16* __restrict__ bias, const bf16* __restrict__ base,
                                                     bf16* __restrict__ dst, int relu_mode)
{
  __shared__ __align__(16) bf16 tile[10*18*CC];
  __shared__ __align__(16) float wt[48*CC];
  int tx0 = blockIdx.x * 16, ty0 = blockIdx.y * 8, bb = blockIdx.z;
  int tid = threadIdx.x;
  for (int idx = tid; idx < 10*18*CC; idx += 256){
    int yy = idx / (18*CC); int rem = idx - yy*(18*CC);
    int xx = rem / CC; int ci = rem - xx*CC;
    int gy = ty0 + yy - 1, gx = tx0 + xx - 1;
    bf16 v = f2b(0.f);
    if (gy >= 0 && gy < HH && gx >= 0 && gx < WWID)
      v = src[(((long)bb*HH + gy)*WWID + gx)*CC + ci];
    tile[idx] = v;
  }
  int pg = tid >> 3, cg = tid & 7;
  int py = pg >> 2, px0 = (pg & 3) * 4;
  int co0 = cg * 12;
  float acc[4][12];
  #pragma unroll
  for (int k = 0; k < 4; ++k)
    #pragma unroll
    for (int u = 0; u < 12; ++u) acc[k][u] = b2f(bias[co0 + u]);
  for (int tap = 0; tap < 9; ++tap){
    int dy = tap / 3, dx = tap - dy*3;
    for (int cc = 0; cc < 2; ++cc){
      __syncthreads();
      for (int idx = tid; idx < 48*CC; idx += 256){
        int rr = idx / CC, c = idx - rr*CC;
        wt[idx] = b2f(w[(long)tap*CC*CC + (long)(cc*48 + rr)*CC + c]);
      }
      __syncthreads();
      const bf16* trow = &tile[((py+dy)*18 + (px0+dx))*CC + cc*48];
      for (int ci = 0; ci < 48; ++ci){
        float a0 = b2f(trow[ci]);
        float a1 = b2f(trow[ci + CC]);
        float a2 = b2f(trow[ci + 2*CC]);
        float a3 = b2f(trow[ci + 3*CC]);
        const float* wr = &wt[ci*CC + co0];
        #pragma unroll
        for (int u = 0; u < 12; ++u){
          float wv = wr[u];
          acc[0][u] += a0*wv; acc[1][u] += a1*wv; acc[2][u] += a2*wv; acc[3][u] += a3*wv;
        }
      }
    }
  }
  #pragma unroll
  for (int k = 0; k < 4; ++k){
    long obase = (((long)bb*HH + ty0+py)*WWID + tx0+px0+k)*CC + co0;
    if (relu_mode){
      #pragma unroll
      for (int u = 0; u < 12; ++u) dst[obase+u] = f2b(fmaxf(acc[k][u], 0.f));
    } else {
      #pragma unroll
      for (int u = 0; u < 12; ++u) dst[obase+u] = f2b(b2f(base[obase+u]) + acc[k][u]);
    }
  }
}

// ---------------- 3x3 conv, 192->192, + exact GELU --------------------------
__global__ __launch_bounds__(256) void convm_kernel(const bf16* __restrict__ src, const bf16* __restrict__ w,
                                                    const bf16* __restrict__ bias, bf16* __restrict__ dst)
{
  __shared__ __align__(16) bf16 tile[10*10*HID];
  __shared__ __align__(16) float wt[32*HID];
  int tx0 = blockIdx.x * 8, ty0 = blockIdx.y * 8, bb = blockIdx.z;
  int tid = threadIdx.x;
  for (int idx = tid; idx < 10*10*HID; idx += 256){
    int yy = idx / (10*HID); int rem = idx - yy*(10*HID);
    int xx = rem / HID; int ci = rem - xx*HID;
    int gy = ty0 + yy - 1, gx = tx0 + xx - 1;
    bf16 v = f2b(0.f);
    if (gy >= 0 && gy < HH && gx >= 0 && gx < WWID)
      v = src[(((long)bb*HH + gy)*WWID + gx)*HID + ci];
    tile[idx] = v;
  }
  int pg = tid >> 4, cg = tid & 15;
  int py = pg >> 1, px0 = (pg & 1) * 4;
  int co0 = cg * 12;
  float acc[4][12];
  #pragma unroll
  for (int k = 0; k < 4; ++k)
    #pragma unroll
    for (int u = 0; u < 12; ++u) acc[k][u] = b2f(bias[co0 + u]);
  for (int tap = 0; tap < 9; ++tap){
    int dy = tap / 3, dx = tap - dy*3;
    for (int cc = 0; cc < 6; ++cc){
      __syncthreads();
      for (int idx = tid; idx < 32*HID; idx += 256){
        int rr = idx / HID, c = idx - rr*HID;
        wt[idx] = b2f(w[(long)tap*HID*HID + (long)(cc*32 + rr)*HID + c]);
      }
      __syncthreads();
      const bf16* trow = &tile[((py+dy)*10 + (px0+dx))*HID + cc*32];
      for (int ci = 0; ci < 32; ++ci){
        float a0 = b2f(trow[ci]);
        float a1 = b2f(trow[ci + HID]);
        float a2 = b2f(trow[ci + 2*HID]);
        float a3 = b2f(trow[ci + 3*HID]);
        const float* wr = &wt[ci*HID + co0];
        #pragma unroll
        for (int u = 0; u < 12; ++u){
          float wv = wr[u];
          acc[0][u] += a0*wv; acc[1][u] += a1*wv; acc[2][u] += a2*wv; acc[3][u] += a3*wv;
        }
      }
    }
  }
  #pragma unroll
  for (int k = 0; k < 4; ++k){
    long obase = (((long)bb*HH + ty0+py)*WWID + tx0+px0+k)*HID + co0;
    #pragma unroll
    for (int u = 0; u < 12; ++u){
      float v = acc[k][u];
      dst[obase+u] = f2b(0.5f * v * (1.f + erff(v * 0.7071067811865476f)));
    }
  }
}

// ---------------- proj (96x96) + roll-back(+4,+4) + shortcut -> bf16 xmid ---
// Low-pressure inner loop (no hoisted uint4 arrays -> no spills). Padded LDS.
#define PPITCH (CC+8)      // 104 elements, 208 B (16B-aligned rows)
__global__ __launch_bounds__(256) void proj_kernel(const bf16* __restrict__ img, const bf16* __restrict__ pw,
                                                   const bf16* __restrict__ pb, const bf16* __restrict__ xorig,
                                                   bf16* __restrict__ xmid)
{
  __shared__ __align__(16) bf16 rows[64][PPITCH];
  __shared__ __align__(16) bf16 wsm[CC][PPITCH];
  long pix0 = (long)blockIdx.x * 64;
  int tid = threadIdx.x;
  for (int idx = tid; idx < 64*CC; idx += 256){
    int pp = idx / CC, c = idx - pp*CC;
    long pix = pix0 + pp;
    int b = (int)(pix >> 16); int hw = (int)(pix & 65535);
    int h = hw >> 8, wc = hw & 255;
    int sh = (h - SHIFTV) & 255, sw = (wc - SHIFTV) & 255;
    rows[pp][c] = img[(((long)b*HH + sh)*WWID + sw)*CC + c];
  }
  for (int idx = tid; idx < CC*CC; idx += 256){
    int rr = idx / CC, c = idx - rr*CC;
    wsm[rr][c] = pw[idx];
  }
  __syncthreads();
  int ty = tid >> 4, tx = tid & 15;
  int r0 = ty*4;
  float acc[4][6];
  #pragma unroll
  for (int j = 0; j < 6; ++j){
    float bv = b2f(pb[tx + 16*j]);
    #pragma unroll
    for (int i = 0; i < 4; ++i) acc[i][j] = bv;
  }
  for (int kk = 0; kk < 12; ++kk){
    uint4 a0 = ((const uint4*)rows[r0+0])[kk];
    uint4 a1 = ((const uint4*)rows[r0+1])[kk];
    uint4 a2 = ((const uint4*)rows[r0+2])[kk];
    uint4 a3 = ((const uint4*)rows[r0+3])[kk];
    #pragma unroll
    for (int j = 0; j < 6; ++j){
      uint4 wv = ((const uint4*)wsm[tx + 16*j])[kk];
      acc[0][j] = dot8(a0, wv, acc[0][j]);
      acc[1][j] = dot8(a1, wv, acc[1][j]);
      acc[2][j] = dot8(a2, wv, acc[2][j]);
      acc[3][j] = dot8(a3, wv, acc[3][j]);
    }
  }
  #pragma unroll
  for (int i = 0; i < 4; ++i){
    long pix = pix0 + r0 + i;
    #pragma unroll
    for (int j = 0; j < 6; ++j){
      long oi = pix*CC + tx + 16*j;
      xmid[oi] = f2b(b2f(xorig[oi]) + acc[i][j]);
    }
  }
}

// ---------------- fc1: 96->192 + exact GELU ---------------------------------
__global__ __launch_bounds__(256) void fc1_kernel(const bf16* __restrict__ src, const bf16* __restrict__ w,
                                                  const bf16* __restrict__ bias, bf16* __restrict__ dst)
{
  __shared__ __align__(16) bf16 rows[64][PPITCH];
  __shared__ __align__(16) bf16 wsm[HID][PPITCH];
  long pix0 = (long)blockIdx.x * 64;
  int tid = threadIdx.x;
  for (int idx = tid; idx < 64*CC; idx += 256){
    int pp = idx / CC, c = idx - pp*CC;
    rows[pp][c] = src[(pix0 + pp)*CC + c];
  }
  for (int idx = tid; idx < HID*CC; idx += 256){
    int rr = idx / CC, c = idx - rr*CC;
    wsm[rr][c] = w[idx];
  }
  __syncthreads();
  int ty = tid >> 4, tx = tid & 15;
  int r0 = ty*4;
  float acc[4][12];
  #pragma unroll
  for (int j = 0; j < 12; ++j){
    float bv = b2f(bias[tx + 16*j]);
    #pragma unroll
    for (int i = 0; i < 4; ++i) acc[i][j] = bv;
  }
  for (int kk = 0; kk < 12; ++kk){
    uint4 a0 = ((const uint4*)rows[r0+0])[kk];
    uint4 a1 = ((const uint4*)rows[r0+1])[kk];
    uint4 a2 = ((const uint4*)rows[r0+2])[kk];
    uint4 a3 = ((const uint4*)rows[r0+3])[kk];
    #pragma unroll
    for (int j = 0; j < 12; ++j){
      uint4 wv = ((const uint4*)wsm[tx + 16*j])[kk];
      acc[0][j] = dot8(a0, wv, acc[0][j]);
      acc[1][j] = dot8(a1, wv, acc[1][j]);
      acc[2][j] = dot8(a2, wv, acc[2][j]);
      acc[3][j] = dot8(a3, wv, acc[3][j]);
    }
  }
  #pragma unroll
  for (int i = 0; i < 4; ++i){
    long pix = pix0 + r0 + i;
    #pragma unroll
    for (int j = 0; j < 12; ++j){
      float v = acc[i][j];
      dst[pix*HID + tx + 16*j] = f2b(0.5f * v * (1.f + erff(v * 0.7071067811865476f)));
    }
  }
}

// ---------------- fc2: 192->96 + bf16 xmid residual -> out (flag dtype) -----
#define FPITCH (HID+8)     // 200 elements, 400 B
__global__ __launch_bounds__(256) void fc2_kernel(const bf16* __restrict__ src, const bf16* __restrict__ w,
                                                  const bf16* __restrict__ bias, const bf16* __restrict__ xmid,
                                                  void* __restrict__ outv, const int* __restrict__ flag)
{
  __shared__ __align__(16) bf16 rows[64][FPITCH];
  __shared__ __align__(16) bf16 wsm[CC][FPITCH];
  long pix0 = (long)blockIdx.x * 64;
  int tid = threadIdx.x;
  for (int idx = tid; idx < 64*HID; idx += 256){
    int pp = idx / HID, c = idx - pp*HID;
    rows[pp][c] = src[(pix0 + pp)*HID + c];
  }
  for (int idx = tid; idx < CC*HID; idx += 256){
    int rr = idx / HID, c = idx - rr*HID;
    wsm[rr][c] = w[idx];
  }
  __syncthreads();
  int ty = tid >> 4, tx = tid & 15;
  int r0 = ty*4;
  float acc[4][6];
  #pragma unroll
  for (int j = 0; j < 6; ++j){
    float bv = b2f(bias[tx + 16*j]);
    #pragma unroll
    for (int i = 0; i < 4; ++i) acc[i][j] = bv;
  }
  for (int kk = 0; kk < 24; ++kk){
    uint4 a0 = ((const uint4*)rows[r0+0])[kk];
    uint4 a1 = ((const uint4*)rows[r0+1])[kk];
    uint4 a2 = ((const uint4*)rows[r0+2])[kk];
    uint4 a3 = ((const uint4*)rows[r0+3])[kk];
    #pragma unroll
    for (int j = 0; j < 6; ++j){
      uint4 wv = ((const uint4*)wsm[tx + 16*j])[kk];
      acc[0][j] = dot8(a0, wv, acc[0][j]);
      acc[1][j] = dot8(a1, wv, acc[1][j]);
      acc[2][j] = dot8(a2, wv, acc[2][j]);
      acc[3][j] = dot8(a3, wv, acc[3][j]);
    }
  }
  int f = *flag;
  #pragma unroll
  for (int i = 0; i < 4; ++i){
    long pix = pix0 + r0 + i;
    #pragma unroll
    for (int j = 0; j < 6; ++j){
      long oi = pix*CC + tx + 16*j;
      float v = b2f(xmid[oi]) + acc[i][j];
      if (f) ((float*)outv)[oi] = v;
      else   ((bf16*)outv)[oi] = f2b(v);
    }
  }
}

extern "C" void kernel_launch(void* const* d_in, const int* in_sizes, int n_in,
                              void* d_out, int out_size, void* d_ws, size_t ws_size,
                              hipStream_t stream)
{
  long cum[22]; cum[0] = 0;
  for (int i = 0; i < 21; ++i) cum[i+1] = cum[i] + in_sizes[i];
  long total = cum[21];

  CvtArgs a;
  for (int i = 0; i < 21; ++i) a.src[i] = d_in[i];
  for (int i = 0; i < 22; ++i) a.cum[i] = cum[i];

  char* ws = (char*)d_ws;
  int*  flag   = (int*)ws;
  bf16* packed = (bf16*)(ws + 1048576);           // [1MB, ~50.4MB)

  detect_kernel<<<1, 256, 0, stream>>>((const unsigned*)d_in[0], flag);
  cvt_kernel<<<(int)((total + 255) / 256), 256, 0, stream>>>(a, flag, packed, total);

  #define PP(i) (packed + cum[i])
  const bf16* xc    = PP(0);
  const bf16* rc    = PP(1);
  const bf16* n1g   = PP(2);
  const bf16* n1b   = PP(3);
  const bf16* qkv_w = PP(4);
  const bf16* qkv_b = PP(5);
  const bf16* lsc   = PP(6);
  const bf16* gat   = PP(7);
  const bf16* rpbt  = PP(8);
  const bf16* tw    = PP(9);
  const bf16* tb    = PP(10);
  const bf16* pw    = PP(11);
  const bf16* pb    = PP(12);
  const bf16* n2g   = PP(13);
  const bf16* n2b   = PP(14);
  const bf16* f1w   = PP(15);
  const bf16* f1b   = PP(16);
  const bf16* cmw   = PP(17);
  const bf16* cmb   = PP(18);
  const bf16* f2w   = PP(19);
  const bf16* f2bp  = PP(20);

  // --- workspace layout (peak 123 MB) ---------------------------------------
  bf16* xn   = (bf16*)(ws + 53477376);            // 51 MB
  bf16* rn   = (bf16*)(ws + 78643200);            // 75 MB
  bf16* img  = (bf16*)(ws + 103809024);           // 99 MB
  bf16* rtr  = xn;                                // trunk scratch (xn dead after attn)
  bf16* xmid = xn;                                // proj out (rtr dead after trunk)
  bf16* ln2o = rn;                                // LN2 out (rn dead after attn)
  bf16* h1   = (bf16*)(ws + 1048576);             // [1,49)MB (xc/rc dead by fc1)
  bf16* hc   = rn;                                // [75,123)MB (ln2o+img dead by convm)

  ln1_kernel<<<65536, 256, 0, stream>>>(xc, rc, n1g, n1b, xn, rn);
  attn_kernel<<<2048, 256, 0, stream>>>(xn, rn, qkv_w, qkv_b, lsc, gat, rpbt, img);

  conv96_kernel<<<dim3(16,32,2), 256, 0, stream>>>(img, tw + 0*82944, tb + 0,   nullptr, rtr, 1);
  conv96_kernel<<<dim3(16,32,2), 256, 0, stream>>>(rtr, tw + 1*82944, tb + 96,  img,     img, 0);
  conv96_kernel<<<dim3(16,32,2), 256, 0, stream>>>(img, tw + 2*82944, tb + 192, nullptr, rtr, 1);
  conv96_kernel<<<dim3(16,32,2), 256, 0, stream>>>(rtr, tw + 3*82944, tb + 288, img,     img, 0);

  proj_kernel<<<2048, 256, 0, stream>>>(img, pw, pb, xc, xmid);
  ln2_kernel<<<32768, 256, 0, stream>>>(xmid, n2g, n2b, ln2o);
  fc1_kernel<<<2048, 256, 0, stream>>>(ln2o, f1w, f1b, h1);
  convm_kernel<<<dim3(32,32,2), 256, 0, stream>>>(h1, cmw, cmb, hc);
  fc2_kernel<<<2048, 256, 0, stream>>>(hc, f2w, f2bp, xmid, d_out, flag);
}

// Round 5
// 1925.562 us; speedup vs baseline: 9.5709x; 2.2275x over previous
//
#include <hip/hip_runtime.h>
#include <hip/hip_bf16.h>

// Shapes (fixed by the reference)
#define BB 2
#define HH 256
#define WWID 256
#define CC 96
#define NHEADS 6
#define WSZ 8
#define SHIFTV 4
#define HDIM 16
#define NTOK 64
#define HID 192
#define LL 65536   // H*W

using bf16 = __hip_bfloat16;
typedef short short8v __attribute__((ext_vector_type(8)));
typedef float float4v __attribute__((ext_vector_type(4)));

__device__ __forceinline__ float b2f(bf16 v){ return __bfloat162float(v); }
__device__ __forceinline__ bf16  f2b(float f){ return __float2bfloat16(f); }
__device__ __forceinline__ float blo(unsigned u){ union {unsigned x; float f;} c; c.x = u << 16; return c.f; }
__device__ __forceinline__ float bhi(unsigned u){ union {unsigned x; float f;} c; c.x = u & 0xffff0000u; return c.f; }

__device__ __forceinline__ float dot8(uint4 a, uint4 b, float acc){
  acc += blo(a.x)*blo(b.x); acc += bhi(a.x)*bhi(b.x);
  acc += blo(a.y)*blo(b.y); acc += bhi(a.y)*bhi(b.y);
  acc += blo(a.z)*blo(b.z); acc += bhi(a.z)*bhi(b.z);
  acc += blo(a.w)*blo(b.w); acc += bhi(a.w)*bhi(b.w);
  return acc;
}

// ---------------- input dtype detection -------------------------------------
__global__ void detect_kernel(const unsigned* __restrict__ x, int* __restrict__ flag){
  __shared__ int s[256];
  int t = threadIdx.x;
  int cnt = 0;
  #pragma unroll
  for (int i = 0; i < 4; ++i){
    unsigned u = x[t*4 + i];
    unsigned e = (u >> 7) & 0xFFu;
    cnt += (e >= 118u && e <= 130u) ? 1 : 0;
  }
  s[t] = cnt; __syncthreads();
  for (int m = 128; m > 0; m >>= 1){ if (t < m) s[t] += s[t+m]; __syncthreads(); }
  if (t == 0) *flag = (s[0] < 512) ? 1 : 0;
}

// ---------------- convert all inputs into one packed bf16 block -------------
struct CvtArgs { const void* src[21]; long cum[22]; };

__global__ void cvt_kernel(CvtArgs a, const int* __restrict__ flag,
                           bf16* __restrict__ dst, long total){
  long k = (long)blockIdx.x * 256 + threadIdx.x;
  if (k >= total) return;
  int lo = 0;
  #pragma unroll
  for (int i = 0; i < 21; ++i) if (k >= a.cum[i+1]) lo = i+1;
  long e = k - a.cum[lo];
  if (*flag) dst[k] = f2b(((const float*)a.src[lo])[e]);
  else       dst[k] = ((const bf16*)a.src[lo])[e];
}

// ---------------- weight transpose: w[tap][cin][cout] -> wt[tap][cout][cin] -
__global__ void wtrans_kernel(const bf16* __restrict__ w, bf16* __restrict__ wt,
                              int CIN, int COUT, long total){
  long k = (long)blockIdx.x * 256 + threadIdx.x;
  if (k >= total) return;
  int pc = CIN*COUT;
  int tap = (int)(k / pc); int rem = (int)(k - (long)tap*pc);
  int co = rem / CIN; int ci = rem - co*CIN;
  wt[k] = w[((long)tap*CIN + ci)*COUT + co];
}

// ---------------- LayerNorm1 on x and ref (bf16 in -> bf16 out) -------------
__global__ __launch_bounds__(256) void ln1_kernel(const bf16* __restrict__ x, const bf16* __restrict__ ref,
                                                  const bf16* __restrict__ g, const bf16* __restrict__ bt,
                                                  bf16* __restrict__ xn, bf16* __restrict__ rn)
{
  int wave = threadIdx.x >> 6, lane = threadIdx.x & 63;
  long row = (long)blockIdx.x * 4 + wave;         // 0 .. 2*BB*LL-1
  const bf16* src; bf16* dst; long r;
  if (row < (long)BB*LL){ src = x; dst = xn; r = row; }
  else                  { src = ref; dst = rn; r = row - (long)BB*LL; }
  const bf16* p = src + r*CC;
  float v0 = b2f(p[lane]);
  float v1 = (lane < 32) ? b2f(p[64+lane]) : 0.f;
  float s = v0 + v1;
  #pragma unroll
  for (int m = 32; m >= 1; m >>= 1) s += __shfl_xor(s, m, 64);
  float mu = s * (1.f/CC);
  float d0 = v0 - mu, d1 = v1 - mu;
  float ss = d0*d0 + ((lane < 32) ? d1*d1 : 0.f);
  #pragma unroll
  for (int m = 32; m >= 1; m >>= 1) ss += __shfl_xor(ss, m, 64);
  float rstd = rsqrtf(ss * (1.f/CC) + 1e-5f);
  bf16* q = dst + r*CC;
  q[lane] = f2b(d0 * rstd * b2f(g[lane]) + b2f(bt[lane]));
  if (lane < 32) q[64+lane] = f2b(d1 * rstd * b2f(g[64+lane]) + b2f(bt[64+lane]));
}

// ---------------- LayerNorm2 (bf16 in -> bf16 out) --------------------------
__global__ __launch_bounds__(256) void ln2_kernel(const bf16* __restrict__ xin,
                                                  const bf16* __restrict__ g, const bf16* __restrict__ bt,
                                                  bf16* __restrict__ out)
{
  int wave = threadIdx.x >> 6, lane = threadIdx.x & 63;
  long r = (long)blockIdx.x * 4 + wave;           // 0 .. BB*LL-1
  const bf16* p = xin + r*CC;
  float v0 = b2f(p[lane]);
  float v1 = (lane < 32) ? b2f(p[64+lane]) : 0.f;
  float s = v0 + v1;
  #pragma unroll
  for (int m = 32; m >= 1; m >>= 1) s += __shfl_xor(s, m, 64);
  float mu = s * (1.f/CC);
  float d0 = v0 - mu, d1 = v1 - mu;
  float ss = d0*d0 + ((lane < 32) ? d1*d1 : 0.f);
  #pragma unroll
  for (int m = 32; m >= 1; m >>= 1) ss += __shfl_xor(ss, m, 64);
  float rstd = rsqrtf(ss * (1.f/CC) + 1e-5f);
  bf16* q = out + r*CC;
  q[lane] = f2b(d0 * rstd * b2f(g[lane]) + b2f(bt[lane]));
  if (lane < 32) q[64+lane] = f2b(d1 * rstd * b2f(g[64+lane]) + b2f(bt[64+lane]));
}

// ---------------- Fused window attention (both paths, gated) ----------------
__global__ __launch_bounds__(256) void attn_kernel(const bf16* __restrict__ xn, const bf16* __restrict__ rn,
                                                   const bf16* __restrict__ qkv_w, const bf16* __restrict__ qkv_b,
                                                   const bf16* __restrict__ lsc, const bf16* __restrict__ gat,
                                                   const bf16* __restrict__ rpbt, bf16* __restrict__ img)
{
  __shared__ __align__(16) bf16 sx[NTOK][CC];
  __shared__ __align__(16) bf16 sr[NTOK][CC];
  __shared__ __align__(16) bf16 wb[48][CC];
  __shared__ float sbias[48];
  __shared__ __align__(16) float qh[NTOK][HDIM];
  __shared__ float kh[NTOK][HDIM], vh[NTOK][HDIM], krh[NTOK][HDIM], vrh[NTOK][HDIM];

  int widx = blockIdx.x;
  int b  = widx >> 10;
  int wib = widx & 1023;
  int wh = wib >> 5, ww = wib & 31;
  int tid = threadIdx.x;

  for (int idx = tid; idx < NTOK*CC; idx += 256){
    int n = idx / CC, c = idx - n*CC;
    int i = n >> 3, j = n & 7;
    int h0 = (wh*8 + i + SHIFTV) & 255;
    int w0 = (ww*8 + j + SHIFTV) & 255;
    long base = (((long)b*HH + h0)*WWID + w0)*CC + c;
    sx[n][c] = xn[base];
    sr[n][c] = rn[base];
  }
  __syncthreads();

  int n  = tid >> 2;
  int qq = tid & 3;
  int i1 = n >> 3, j1 = n & 7;
  int rl1 = (wh < 31) ? 0 : (i1 < 4 ? 1 : 2);
  int cl1 = (ww < 31) ? 0 : (j1 < 4 ? 1 : 2);
  int reg1 = rl1*3 + cl1;

  for (int h = 0; h < NHEADS; ++h){
    for (int idx = tid; idx < 48*CC; idx += 256){
      int rr = idx / CC, c = idx - rr*CC;
      int o = (rr >> 4)*CC + h*HDIM + (rr & 15);
      wb[rr][c] = qkv_w[(long)o*CC + c];
    }
    if (tid < 48){
      int o = (tid >> 4)*CC + h*HDIM + (tid & 15);
      sbias[tid] = b2f(qkv_b[o]);
    }
    __syncthreads();

    for (int idx = tid; idx < 5*NTOK*HDIM; idx += 256){
      int which = idx >> 10;
      int rem = idx & 1023;
      int nn = rem >> 4, d = rem & 15;
      int wrow = (which == 0) ? d : (which == 1 || which == 3) ? 16 + d : 32 + d;
      const bf16* srow = (which < 3) ? sx[nn] : sr[nn];
      const uint4* a = (const uint4*)srow;
      const uint4* wv = (const uint4*)wb[wrow];
      float acc = sbias[wrow];
      #pragma unroll
      for (int kk = 0; kk < 12; ++kk) acc = dot8(a[kk], wv[kk], acc);
      float* dstf = (which==0) ? &qh[0][0] : (which==1) ? &kh[0][0] : (which==2) ? &vh[0][0]
                    : (which==3) ? &krh[0][0] : &vrh[0][0];
      dstf[(nn << 4) + d] = acc;
    }
    __syncthreads();

    if (tid < 192){
      int rr = tid & 63;
      float* row = (tid < 64) ? qh[rr] : (tid < 128) ? kh[rr] : krh[rr];
      float s = 0.f;
      #pragma unroll
      for (int d = 0; d < 16; ++d) s += row[d]*row[d];
      float inv = 1.f / fmaxf(sqrtf(s), 1e-12f);
      #pragma unroll
      for (int d = 0; d < 16; ++d) row[d] *= inv;
    }
    __syncthreads();

    float ls = expf(fminf(b2f(lsc[h]), 4.605170185988091f));
    float gv = b2f(gat[h]);
    float g = 1.f / (1.f + expf(-gv));

    float qr[16];
    #pragma unroll
    for (int d = 0; d < 16; ++d) qr[d] = qh[n][d];

    float s1[16], s2[16];
    #pragma unroll
    for (int u = 0; u < 16; ++u){
      int m = qq*16 + u;
      float a1 = 0.f, a2 = 0.f;
      #pragma unroll
      for (int d = 0; d < 16; ++d){ a1 += qr[d]*kh[m][d]; a2 += qr[d]*krh[m][d]; }
      int i2 = m >> 3, j2 = m & 7;
      float rp = b2f(rpbt[((i1 - i2 + 7)*15 + (j1 - j2 + 7))*NHEADS + h]);
      int rl2 = (wh < 31) ? 0 : (i2 < 4 ? 1 : 2);
      int cl2 = (ww < 31) ? 0 : (j2 < 4 ? 1 : 2);
      float msk = (reg1 != rl2*3 + cl2) ? -100.f : 0.f;
      s1[u] = a1*ls + rp + msk;
      s2[u] = a2*ls + rp + msk;
    }
    float mx1 = -1e30f, mx2 = -1e30f;
    #pragma unroll
    for (int u = 0; u < 16; ++u){ mx1 = fmaxf(mx1, s1[u]); mx2 = fmaxf(mx2, s2[u]); }
    #pragma unroll
    for (int m = 1; m < 4; m <<= 1){ mx1 = fmaxf(mx1, __shfl_xor(mx1, m, 64)); mx2 = fmaxf(mx2, __shfl_xor(mx2, m, 64)); }
    float sm1 = 0.f, sm2 = 0.f;
    #pragma unroll
    for (int u = 0; u < 16; ++u){ s1[u] = expf(s1[u]-mx1); sm1 += s1[u]; s2[u] = expf(s2[u]-mx2); sm2 += s2[u]; }
    #pragma unroll
    for (int m = 1; m < 4; m <<= 1){ sm1 += __shfl_xor(sm1, m, 64); sm2 += __shfl_xor(sm2, m, 64); }
    float p1s = (1.f - g) / sm1, p2s = g / sm2;

    float po[16];
    #pragma unroll
    for (int d = 0; d < 16; ++d) po[d] = 0.f;
    #pragma unroll
    for (int u = 0; u < 16; ++u){
      int m = qq*16 + u;
      float p1 = s1[u]*p1s, p2 = s2[u]*p2s;
      #pragma unroll
      for (int d = 0; d < 16; ++d) po[d] += p1*vh[m][d] + p2*vrh[m][d];
    }
    #pragma unroll
    for (int m = 1; m < 4; m <<= 1){
      #pragma unroll
      for (int d = 0; d < 16; ++d) po[d] += __shfl_xor(po[d], m, 64);
    }
    {
      int hs = wh*8 + i1, wsp = ww*8 + j1;
      long obase = (((long)b*HH + hs)*WWID + wsp)*CC + h*HDIM + qq*4;
      #pragma unroll
      for (int d = 0; d < 4; ++d) img[obase + d] = f2b(po[qq*4 + d]);
    }
    __syncthreads();
  }
}

// ---------------- MFMA implicit-GEMM 3x3 conv (NHWC, pad 1) -----------------
// Block: 8x8 output pixels (M=64) x NB couts. 4 waves as 2m x 2n; each wave
// 2 m-tiles x 3 n-tiles of 16x16x32 MFMA. Weights pre-transposed wt[tap][cout][cin].
// MODE 0: relu; MODE 1: dst = base + conv; MODE 2: exact gelu.
template<int CIN, int COUT, int MODE>
__global__ __launch_bounds__(256) void convmfma_kernel(const bf16* __restrict__ src,
                                                       const bf16* __restrict__ wt,
                                                       const bf16* __restrict__ bias,
                                                       const bf16* __restrict__ base,
                                                       bf16* __restrict__ dst)
{
  constexpr int NB = 96;
  constexpr int AP = CIN + 8;          // padded channel pitch (elements)
  constexpr int C8 = CIN / 8;
  __shared__ __align__(16) bf16 act[100*AP];
  __shared__ __align__(16) bf16 wsm[NB*AP];

  int tid = threadIdx.x;
  int z = blockIdx.z;
  int bb = (COUT == NB) ? z : (z >> 1);
  int n0 = (COUT == NB) ? 0 : ((z & 1) * NB);
  int tx0 = blockIdx.x * 8, ty0 = blockIdx.y * 8;

  // stage activation halo tile 10x10 x CIN
  for (int idx = tid; idx < 100*C8; idx += 256){
    int pp = idx / C8, c8 = idx - pp*C8;
    int iy = pp / 10, ix = pp - iy*10;
    int gy = ty0 + iy - 1, gx = tx0 + ix - 1;
    uint4 v = make_uint4(0,0,0,0);
    if ((unsigned)gy < (unsigned)HH && (unsigned)gx < (unsigned)WWID)
      v = *(const uint4*)&src[(((long)bb*HH + gy)*WWID + gx)*CIN + c8*8];
    *(uint4*)&act[pp*AP + c8*8] = v;
  }

  int wv = tid >> 6, lane = tid & 63;
  int wm = wv >> 1, wn = wv & 1;
  int ml = lane & 15, quad = lane >> 4;

  float4v acc[2][3];
  #pragma unroll
  for (int nt = 0; nt < 3; ++nt){
    float bv = b2f(bias[n0 + wn*48 + nt*16 + ml]);
    #pragma unroll
    for (int mt = 0; mt < 2; ++mt)
      acc[mt][nt] = (float4v){bv, bv, bv, bv};
  }

  int pl0 = wm*32 + ml, pl1 = pl0 + 16;
  int py0 = pl0 >> 3, px0 = pl0 & 7;
  int py1 = pl1 >> 3, px1 = pl1 & 7;

  for (int tap = 0; tap < 9; ++tap){
    __syncthreads();
    const bf16* wsrc = wt + ((long)tap*COUT + n0)*CIN;
    for (int idx = tid; idx < NB*C8; idx += 256){
      int rr = idx / C8, c8 = idx - rr*C8;
      *(uint4*)&wsm[rr*AP + c8*8] = *(const uint4*)&wsrc[rr*CIN + c8*8];
    }
    __syncthreads();
    int dy = tap / 3, dx = tap - dy*3;
    int ar0 = ((py0+dy)*10 + px0 + dx)*AP;
    int ar1 = ((py1+dy)*10 + px1 + dx)*AP;
    int br0 = (wn*48 + ml)*AP, br1 = br0 + 16*AP, br2 = br0 + 32*AP;
    #pragma unroll
    for (int kc = 0; kc < CIN/32; ++kc){
      int ko = kc*32 + quad*8;
      short8v a0 = *(const short8v*)&act[ar0 + ko];
      short8v a1 = *(const short8v*)&act[ar1 + ko];
      short8v b0 = *(const short8v*)&wsm[br0 + ko];
      short8v b1 = *(const short8v*)&wsm[br1 + ko];
      short8v b2 = *(const short8v*)&wsm[br2 + ko];
      acc[0][0] = __builtin_amdgcn_mfma_f32_16x16x32_bf16(a0, b0, acc[0][0], 0, 0, 0);
      acc[0][1] = __builtin_amdgcn_mfma_f32_16x16x32_bf16(a0, b1, acc[0][1], 0, 0, 0);
      acc[0][2] = __builtin_amdgcn_mfma_f32_16x16x32_bf16(a0, b2, acc[0][2], 0, 0, 0);
      acc[1][0] = __builtin_amdgcn_mfma_f32_16x16x32_bf16(a1, b0, acc[1][0], 0, 0, 0);
      acc[1][1] = __builtin_amdgcn_mfma_f32_16x16x32_bf16(a1, b1, acc[1][1], 0, 0, 0);
      acc[1][2] = __builtin_amdgcn_mfma_f32_16x16x32_bf16(a1, b2, acc[1][2], 0, 0, 0);
    }
  }

  // epilogue: C/D layout col=lane&15 (cout), row=quad*4+r (pixel)
  #pragma unroll
  for (int mt = 0; mt < 2; ++mt){
    #pragma unroll
    for (int r = 0; r < 4; ++r){
      int pl = wm*32 + mt*16 + quad*4 + r;
      int py = pl >> 3, px = pl & 7;
      long ob = (((long)bb*HH + ty0+py)*WWID + tx0+px)*COUT + n0 + wn*48 + ml;
      #pragma unroll
      for (int nt = 0; nt < 3; ++nt){
        float v = acc[mt][nt][r];
        long o = ob + nt*16;
        if (MODE == 0)      dst[o] = f2b(fmaxf(v, 0.f));
        else if (MODE == 1) dst[o] = f2b(b2f(base[o]) + v);
        else                dst[o] = f2b(0.5f * v * (1.f + erff(v * 0.7071067811865476f)));
      }
    }
  }
}

// ---------------- proj (96x96) + roll-back(+4,+4) + shortcut -> bf16 xmid ---
#define PPITCH (CC+8)
__global__ __launch_bounds__(256) void proj_kernel(const bf16* __restrict__ img, const bf16* __restrict__ pw,
                                                   const bf16* __restrict__ pb, const bf16* __restrict__ xorig,
                                                   bf16* __restrict__ xmid)
{
  __shared__ __align__(16) bf16 rows[64][PPITCH];
  __shared__ __align__(16) bf16 wsm[CC][PPITCH];
  long pix0 = (long)blockIdx.x * 64;
  int tid = threadIdx.x;
  for (int idx = tid; idx < 64*CC; idx += 256){
    int pp = idx / CC, c = idx - pp*CC;
    long pix = pix0 + pp;
    int b = (int)(pix >> 16); int hw = (int)(pix & 65535);
    int h = hw >> 8, wc = hw & 255;
    int sh = (h - SHIFTV) & 255, sw = (wc - SHIFTV) & 255;
    rows[pp][c] = img[(((long)b*HH + sh)*WWID + sw)*CC + c];
  }
  for (int idx = tid; idx < CC*CC; idx += 256){
    int rr = idx / CC, c = idx - rr*CC;
    wsm[rr][c] = pw[idx];
  }
  __syncthreads();
  int ty = tid >> 4, tx = tid & 15;
  int r0 = ty*4;
  float acc[4][6];
  #pragma unroll
  for (int j = 0; j < 6; ++j){
    float bv = b2f(pb[tx + 16*j]);
    #pragma unroll
    for (int i = 0; i < 4; ++i) acc[i][j] = bv;
  }
  for (int kk = 0; kk < 12; ++kk){
    uint4 a0 = ((const uint4*)rows[r0+0])[kk];
    uint4 a1 = ((const uint4*)rows[r0+1])[kk];
    uint4 a2 = ((const uint4*)rows[r0+2])[kk];
    uint4 a3 = ((const uint4*)rows[r0+3])[kk];
    #pragma unroll
    for (int j = 0; j < 6; ++j){
      uint4 wv = ((const uint4*)wsm[tx + 16*j])[kk];
      acc[0][j] = dot8(a0, wv, acc[0][j]);
      acc[1][j] = dot8(a1, wv, acc[1][j]);
      acc[2][j] = dot8(a2, wv, acc[2][j]);
      acc[3][j] = dot8(a3, wv, acc[3][j]);
    }
  }
  #pragma unroll
  for (int i = 0; i < 4; ++i){
    long pix = pix0 + r0 + i;
    #pragma unroll
    for (int j = 0; j < 6; ++j){
      long oi = pix*CC + tx + 16*j;
      xmid[oi] = f2b(b2f(xorig[oi]) + acc[i][j]);
    }
  }
}

// ---------------- fc1: 96->192 + exact GELU ---------------------------------
__global__ __launch_bounds__(256) void fc1_kernel(const bf16* __restrict__ src, const bf16* __restrict__ w,
                                                  const bf16* __restrict__ bias, bf16* __restrict__ dst)
{
  __shared__ __align__(16) bf16 rows[64][PPITCH];
  __shared__ __align__(16) bf16 wsm[HID][PPITCH];
  long pix0 = (long)blockIdx.x * 64;
  int tid = threadIdx.x;
  for (int idx = tid; idx < 64*CC; idx += 256){
    int pp = idx / CC, c = idx - pp*CC;
    rows[pp][c] = src[(pix0 + pp)*CC + c];
  }
  for (int idx = tid; idx < HID*CC; idx += 256){
    int rr = idx / CC, c = idx - rr*CC;
    wsm[rr][c] = w[idx];
  }
  __syncthreads();
  int ty = tid >> 4, tx = tid & 15;
  int r0 = ty*4;
  float acc[4][12];
  #pragma unroll
  for (int j = 0; j < 12; ++j){
    float bv = b2f(bias[tx + 16*j]);
    #pragma unroll
    for (int i = 0; i < 4; ++i) acc[i][j] = bv;
  }
  for (int kk = 0; kk < 12; ++kk){
    uint4 a0 = ((const uint4*)rows[r0+0])[kk];
    uint4 a1 = ((const uint4*)rows[r0+1])[kk];
    uint4 a2 = ((const uint4*)rows[r0+2])[kk];
    uint4 a3 = ((const uint4*)rows[r0+3])[kk];
    #pragma unroll
    for (int j = 0; j < 12; ++j){
      uint4 wv = ((const uint4*)wsm[tx + 16*j])[kk];
      acc[0][j] = dot8(a0, wv, acc[0][j]);
      acc[1][j] = dot8(a1, wv, acc[1][j]);
      acc[2][j] = dot8(a2, wv, acc[2][j]);
      acc[3][j] = dot8(a3, wv, acc[3][j]);
    }
  }
  #pragma unroll
  for (int i = 0; i < 4; ++i){
    long pix = pix0 + r0 + i;
    #pragma unroll
    for (int j = 0; j < 12; ++j){
      float v = acc[i][j];
      dst[pix*HID + tx + 16*j] = f2b(0.5f * v * (1.f + erff(v * 0.7071067811865476f)));
    }
  }
}

// ---------------- fc2: 192->96 + bf16 xmid residual -> out (flag dtype) -----
#define FPITCH (HID+8)
__global__ __launch_bounds__(256) void fc2_kernel(const bf16* __restrict__ src, const bf16* __restrict__ w,
                                                  const bf16* __restrict__ bias, const bf16* __restrict__ xmid,
                                                  void* __restrict__ outv, const int* __restrict__ flag)
{
  __shared__ __align__(16) bf16 rows[64][FPITCH];
  __shared__ __align__(16) bf16 wsm[CC][FPITCH];
  long pix0 = (long)blockIdx.x * 64;
  int tid = threadIdx.x;
  for (int idx = tid; idx < 64*HID; idx += 256){
    int pp = idx / HID, c = idx - pp*HID;
    rows[pp][c] = src[(pix0 + pp)*HID + c];
  }
  for (int idx = tid; idx < CC*HID; idx += 256){
    int rr = idx / HID, c = idx - rr*HID;
    wsm[rr][c] = w[idx];
  }
  __syncthreads();
  int ty = tid >> 4, tx = tid & 15;
  int r0 = ty*4;
  float acc[4][6];
  #pragma unroll
  for (int j = 0; j < 6; ++j){
    float bv = b2f(bias[tx + 16*j]);
    #pragma unroll
    for (int i = 0; i < 4; ++i) acc[i][j] = bv;
  }
  for (int kk = 0; kk < 24; ++kk){
    uint4 a0 = ((const uint4*)rows[r0+0])[kk];
    uint4 a1 = ((const uint4*)rows[r0+1])[kk];
    uint4 a2 = ((const uint4*)rows[r0+2])[kk];
    uint4 a3 = ((const uint4*)rows[r0+3])[kk];
    #pragma unroll
    for (int j = 0; j < 6; ++j){
      uint4 wv = ((const uint4*)wsm[tx + 16*j])[kk];
      acc[0][j] = dot8(a0, wv, acc[0][j]);
      acc[1][j] = dot8(a1, wv, acc[1][j]);
      acc[2][j] = dot8(a2, wv, acc[2][j]);
      acc[3][j] = dot8(a3, wv, acc[3][j]);
    }
  }
  int f = *flag;
  #pragma unroll
  for (int i = 0; i < 4; ++i){
    long pix = pix0 + r0 + i;
    #pragma unroll
    for (int j = 0; j < 6; ++j){
      long oi = pix*CC + tx + 16*j;
      float v = b2f(xmid[oi]) + acc[i][j];
      if (f) ((float*)outv)[oi] = v;
      else   ((bf16*)outv)[oi] = f2b(v);
    }
  }
}

extern "C" void kernel_launch(void* const* d_in, const int* in_sizes, int n_in,
                              void* d_out, int out_size, void* d_ws, size_t ws_size,
                              hipStream_t stream)
{
  long cum[22]; cum[0] = 0;
  for (int i = 0; i < 21; ++i) cum[i+1] = cum[i] + in_sizes[i];
  long total = cum[21];

  CvtArgs a;
  for (int i = 0; i < 21; ++i) a.src[i] = d_in[i];
  for (int i = 0; i < 22; ++i) a.cum[i] = cum[i];

  char* ws = (char*)d_ws;
  int*  flag   = (int*)ws;
  bf16* packed = (bf16*)(ws + 1048576);           // [1MiB, ~50.4MiB)

  detect_kernel<<<1, 256, 0, stream>>>((const unsigned*)d_in[0], flag);
  cvt_kernel<<<(int)((total + 255) / 256), 256, 0, stream>>>(a, flag, packed, total);

  #define PP(i) (packed + cum[i])
  const bf16* xc    = PP(0);
  const bf16* rc    = PP(1);
  const bf16* n1g   = PP(2);
  const bf16* n1b   = PP(3);
  const bf16* qkv_w = PP(4);
  const bf16* qkv_b = PP(5);
  const bf16* lsc   = PP(6);
  const bf16* gat   = PP(7);
  const bf16* rpbt  = PP(8);
  const bf16* tw    = PP(9);
  const bf16* tb    = PP(10);
  const bf16* pw    = PP(11);
  const bf16* pb    = PP(12);
  const bf16* n2g   = PP(13);
  const bf16* n2b   = PP(14);
  const bf16* f1w   = PP(15);
  const bf16* f1b   = PP(16);
  const bf16* cmw   = PP(17);
  const bf16* cmb   = PP(18);
  const bf16* f2w   = PP(19);
  const bf16* f2bp  = PP(20);

  // --- workspace layout (peak ~124 MiB) -------------------------------------
  bf16* wtc  = (bf16*)(ws + 52860928);            // trunk wT  [36][96][96]  (663,552 B)
  bf16* wtm  = (bf16*)(ws + 53524480);            // convm wT  [9][192][192] (663,552 B)
  bf16* xn   = (bf16*)(ws + 54525952);            // 52 MiB
  bf16* rn   = (bf16*)(ws + 79691776);            // 76 MiB
  bf16* img  = (bf16*)(ws + 104857600);           // 100 MiB
  bf16* rtr  = xn;                                // trunk scratch (xn dead after attn)
  bf16* xmid = xn;                                // proj out (rtr dead after trunk)
  bf16* ln2o = rn;                                // LN2 out (rn dead after attn)
  bf16* h1   = (bf16*)(ws + 1048576);             // overlays xc/rc (dead by fc1)
  bf16* hc   = rn;                                // [76,124) MiB (ln2o+img dead by convm)

  wtrans_kernel<<<1296, 256, 0, stream>>>(tw, wtc, 96, 96, 331776);
  wtrans_kernel<<<1296, 256, 0, stream>>>(cmw, wtm, 192, 192, 331776);

  ln1_kernel<<<65536, 256, 0, stream>>>(xc, rc, n1g, n1b, xn, rn);
  attn_kernel<<<2048, 256, 0, stream>>>(xn, rn, qkv_w, qkv_b, lsc, gat, rpbt, img);

  convmfma_kernel<96,96,0><<<dim3(32,32,2), 256, 0, stream>>>(img, wtc + 0*82944, tb + 0,   nullptr, rtr);
  convmfma_kernel<96,96,1><<<dim3(32,32,2), 256, 0, stream>>>(rtr, wtc + 1*82944, tb + 96,  img,     img);
  convmfma_kernel<96,96,0><<<dim3(32,32,2), 256, 0, stream>>>(img, wtc + 2*82944, tb + 192, nullptr, rtr);
  convmfma_kernel<96,96,1><<<dim3(32,32,2), 256, 0, stream>>>(rtr, wtc + 3*82944, tb + 288, img,     img);

  proj_kernel<<<2048, 256, 0, stream>>>(img, pw, pb, xc, xmid);
  ln2_kernel<<<32768, 256, 0, stream>>>(xmid, n2g, n2b, ln2o);
  fc1_kernel<<<2048, 256, 0, stream>>>(ln2o, f1w, f1b, h1);
  convmfma_kernel<192,192,2><<<dim3(32,32,4), 256, 0, stream>>>(h1, wtm, cmb, nullptr, hc);
  fc2_kernel<<<2048, 256, 0, stream>>>(hc, f2w, f2bp, xmid, d_out, flag);
}

// Round 6
// 1130.060 us; speedup vs baseline: 16.3083x; 1.7039x over previous
//
#include <hip/hip_runtime.h>
#include <hip/hip_bf16.h>

// Shapes (fixed by the reference)
#define BB 2
#define HH 256
#define WWID 256
#define CC 96
#define NHEADS 6
#define WSZ 8
#define SHIFTV 4
#define HDIM 16
#define NTOK 64
#define HID 192
#define LL 65536   // H*W

using bf16 = __hip_bfloat16;
typedef short short8v __attribute__((ext_vector_type(8)));
typedef float float4v __attribute__((ext_vector_type(4)));

__device__ __forceinline__ float b2f(bf16 v){ return __bfloat162float(v); }
__device__ __forceinline__ bf16  f2b(float f){ return __float2bfloat16(f); }
__device__ __forceinline__ float blo(unsigned u){ union {unsigned x; float f;} c; c.x = u << 16; return c.f; }
__device__ __forceinline__ float bhi(unsigned u){ union {unsigned x; float f;} c; c.x = u & 0xffff0000u; return c.f; }

__device__ __forceinline__ float dot8(uint4 a, uint4 b, float acc){
  acc += blo(a.x)*blo(b.x); acc += bhi(a.x)*bhi(b.x);
  acc += blo(a.y)*blo(b.y); acc += bhi(a.y)*bhi(b.y);
  acc += blo(a.z)*blo(b.z); acc += bhi(a.z)*bhi(b.z);
  acc += blo(a.w)*blo(b.w); acc += bhi(a.w)*bhi(b.w);
  return acc;
}

// ---------------- input dtype detection -------------------------------------
__global__ void detect_kernel(const unsigned* __restrict__ x, int* __restrict__ flag){
  __shared__ int s[256];
  int t = threadIdx.x;
  int cnt = 0;
  #pragma unroll
  for (int i = 0; i < 4; ++i){
    unsigned u = x[t*4 + i];
    unsigned e = (u >> 7) & 0xFFu;
    cnt += (e >= 118u && e <= 130u) ? 1 : 0;
  }
  s[t] = cnt; __syncthreads();
  for (int m = 128; m > 0; m >>= 1){ if (t < m) s[t] += s[t+m]; __syncthreads(); }
  if (t == 0) *flag = (s[0] < 512) ? 1 : 0;
}

// ---------------- convert all inputs into one packed bf16 block -------------
struct CvtArgs { const void* src[21]; long cum[22]; };

__global__ void cvt_kernel(CvtArgs a, const int* __restrict__ flag,
                           bf16* __restrict__ dst, long total){
  long k = (long)blockIdx.x * 256 + threadIdx.x;
  if (k >= total) return;
  int lo = 0;
  #pragma unroll
  for (int i = 0; i < 21; ++i) if (k >= a.cum[i+1]) lo = i+1;
  long e = k - a.cum[lo];
  if (*flag) dst[k] = f2b(((const float*)a.src[lo])[e]);
  else       dst[k] = ((const bf16*)a.src[lo])[e];
}

// ---------------- weight transpose: w[tap][cin][cout] -> wt[tap][cout][cin] -
__global__ void wtrans_kernel(const bf16* __restrict__ w, bf16* __restrict__ wt,
                              int CIN, int COUT, long total){
  long k = (long)blockIdx.x * 256 + threadIdx.x;
  if (k >= total) return;
  int pc = CIN*COUT;
  int tap = (int)(k / pc); int rem = (int)(k - (long)tap*pc);
  int co = rem / CIN; int ci = rem - co*CIN;
  wt[k] = w[((long)tap*CIN + ci)*COUT + co];
}

// ---------------- LayerNorm1 on x and ref (bf16 in -> bf16 out) -------------
__global__ __launch_bounds__(256) void ln1_kernel(const bf16* __restrict__ x, const bf16* __restrict__ ref,
                                                  const bf16* __restrict__ g, const bf16* __restrict__ bt,
                                                  bf16* __restrict__ xn, bf16* __restrict__ rn)
{
  int wave = threadIdx.x >> 6, lane = threadIdx.x & 63;
  long row = (long)blockIdx.x * 4 + wave;         // 0 .. 2*BB*LL-1
  const bf16* src; bf16* dst; long r;
  if (row < (long)BB*LL){ src = x; dst = xn; r = row; }
  else                  { src = ref; dst = rn; r = row - (long)BB*LL; }
  const bf16* p = src + r*CC;
  float v0 = b2f(p[lane]);
  float v1 = (lane < 32) ? b2f(p[64+lane]) : 0.f;
  float s = v0 + v1;
  #pragma unroll
  for (int m = 32; m >= 1; m >>= 1) s += __shfl_xor(s, m, 64);
  float mu = s * (1.f/CC);
  float d0 = v0 - mu, d1 = v1 - mu;
  float ss = d0*d0 + ((lane < 32) ? d1*d1 : 0.f);
  #pragma unroll
  for (int m = 32; m >= 1; m >>= 1) ss += __shfl_xor(ss, m, 64);
  float rstd = rsqrtf(ss * (1.f/CC) + 1e-5f);
  bf16* q = dst + r*CC;
  q[lane] = f2b(d0 * rstd * b2f(g[lane]) + b2f(bt[lane]));
  if (lane < 32) q[64+lane] = f2b(d1 * rstd * b2f(g[64+lane]) + b2f(bt[64+lane]));
}

// ---------------- LayerNorm2 (bf16 in -> bf16 out) --------------------------
__global__ __launch_bounds__(256) void ln2_kernel(const bf16* __restrict__ xin,
                                                  const bf16* __restrict__ g, const bf16* __restrict__ bt,
                                                  bf16* __restrict__ out)
{
  int wave = threadIdx.x >> 6, lane = threadIdx.x & 63;
  long r = (long)blockIdx.x * 4 + wave;           // 0 .. BB*LL-1
  const bf16* p = xin + r*CC;
  float v0 = b2f(p[lane]);
  float v1 = (lane < 32) ? b2f(p[64+lane]) : 0.f;
  float s = v0 + v1;
  #pragma unroll
  for (int m = 32; m >= 1; m >>= 1) s += __shfl_xor(s, m, 64);
  float mu = s * (1.f/CC);
  float d0 = v0 - mu, d1 = v1 - mu;
  float ss = d0*d0 + ((lane < 32) ? d1*d1 : 0.f);
  #pragma unroll
  for (int m = 32; m >= 1; m >>= 1) ss += __shfl_xor(ss, m, 64);
  float rstd = rsqrtf(ss * (1.f/CC) + 1e-5f);
  bf16* q = out + r*CC;
  q[lane] = f2b(d0 * rstd * b2f(g[lane]) + b2f(bt[lane]));
  if (lane < 32) q[64+lane] = f2b(d1 * rstd * b2f(g[64+lane]) + b2f(bt[64+lane]));
}

// ---------------- Fused window attention, MFMA everywhere -------------------
// One block per window (2048). 4 waves = 4 query M-tiles of 16 tokens.
// All matmuls 16x16x32 bf16 MFMA. d=16 padded to K=32 with zeros for QK^T.
__global__ __launch_bounds__(256) void attn_kernel(const bf16* __restrict__ xn, const bf16* __restrict__ rn,
                                                   const bf16* __restrict__ qkv_w, const bf16* __restrict__ qkv_b,
                                                   const bf16* __restrict__ lsc, const bf16* __restrict__ gat,
                                                   const bf16* __restrict__ rpbt, bf16* __restrict__ img)
{
  __shared__ __align__(16) bf16 sx[NTOK][104];    // 13312 B  window rows (x)
  __shared__ __align__(16) bf16 sr[NTOK][104];    // 13312 B  window rows (ref)
  __shared__ __align__(16) bf16 wb[48][104];      //  9984 B  per-head q,k,v weight rows
  __shared__ float sbias[48];
  __shared__ __align__(16) bf16 qs[NTOK][32];     //  4096 B  q (d 16..31 zero)
  __shared__ __align__(16) bf16 ks[NTOK][32];     //  4096 B  k
  __shared__ __align__(16) bf16 krs[NTOK][32];    //  4096 B  k_ref
  __shared__ __align__(16) bf16 vt[16][72];       //  2304 B  V^T [d][tok]
  __shared__ __align__(16) bf16 vrt[16][72];      //  2304 B  Vr^T
  __shared__ __align__(16) bf16 ps[NTOK][72];     //  9216 B  P (reused path1/path2)
  __shared__ float rpbs[225];                     //   900 B  rpb head slice
  // total 63,812 B

  int widx = blockIdx.x;
  int b = widx >> 10, wib = widx & 1023;
  int wh = wib >> 5, ww = wib & 31;
  int tid = threadIdx.x;
  int wv = tid >> 6, lane = tid & 63;
  int ml = lane & 15, quad = lane >> 4;

  // stage window rows (roll fused), vectorized 16B
  for (int idx = tid; idx < NTOK*12; idx += 256){
    int n = idx / 12, c8 = idx - n*12;
    int i = n >> 3, j = n & 7;
    int h0 = (wh*8 + i + SHIFTV) & 255;
    int w0 = (ww*8 + j + SHIFTV) & 255;
    long base = (((long)b*HH + h0)*WWID + w0)*CC + c8*8;
    *(uint4*)&sx[n][c8*8] = *(const uint4*)&xn[base];
    *(uint4*)&sr[n][c8*8] = *(const uint4*)&rn[base];
  }
  // zero d=16..31 pad of qs/ks/krs (persists across heads)
  for (int idx = tid; idx < 384; idx += 256){
    int arr = idx >> 7, rem = idx & 127;
    int row = rem >> 1, half = rem & 1;
    bf16* bp = (arr == 0) ? &qs[0][0] : (arr == 1) ? &ks[0][0] : &krs[0][0];
    *(uint4*)&bp[row*32 + 16 + half*8] = make_uint4(0,0,0,0);
  }

  for (int h = 0; h < NHEADS; ++h){
    __syncthreads();  // protect wb/rpbs/qs/ks/krs/vt from previous head's reads
    for (int idx = tid; idx < 48*12; idx += 256){
      int rr = idx / 12, c8 = idx - rr*12;
      int o = (rr >> 4)*CC + h*HDIM + (rr & 15);
      *(uint4*)&wb[rr][c8*8] = *(const uint4*)&qkv_w[(long)o*CC + c8*8];
    }
    if (tid < 48){
      int o = (tid >> 4)*CC + h*HDIM + (tid & 15);
      sbias[tid] = b2f(qkv_b[o]);
    }
    if (tid < 225) rpbs[tid] = b2f(rpbt[tid*NHEADS + h]);
    __syncthreads();

    // ---- QKV via MFMA: wave wv owns token rows wv*16..+15 ----
    float4v aq0 = {0,0,0,0}, aq1 = {0,0,0,0}, aq2 = {0,0,0,0};
    float4v ar0 = {0,0,0,0}, ar1 = {0,0,0,0};
    {
      int arow = wv*16 + ml;
      #pragma unroll
      for (int kt = 0; kt < 3; ++kt){
        int ko = kt*32 + quad*8;
        short8v ax = *(const short8v*)&sx[arow][ko];
        short8v av = *(const short8v*)&sr[arow][ko];
        short8v b0 = *(const short8v*)&wb[ml][ko];
        short8v b1 = *(const short8v*)&wb[16+ml][ko];
        short8v b2 = *(const short8v*)&wb[32+ml][ko];
        aq0 = __builtin_amdgcn_mfma_f32_16x16x32_bf16(ax, b0, aq0, 0,0,0);
        aq1 = __builtin_amdgcn_mfma_f32_16x16x32_bf16(ax, b1, aq1, 0,0,0);
        aq2 = __builtin_amdgcn_mfma_f32_16x16x32_bf16(ax, b2, aq2, 0,0,0);
        ar0 = __builtin_amdgcn_mfma_f32_16x16x32_bf16(av, b1, ar0, 0,0,0);
        ar1 = __builtin_amdgcn_mfma_f32_16x16x32_bf16(av, b2, ar1, 0,0,0);
      }
    }
    #pragma unroll
    for (int r = 0; r < 4; ++r){
      int tok = wv*16 + quad*4 + r;
      qs[tok][ml]  = f2b(aq0[r] + sbias[ml]);
      ks[tok][ml]  = f2b(aq1[r] + sbias[16+ml]);
      vt[ml][tok]  = f2b(aq2[r] + sbias[32+ml]);
      krs[tok][ml] = f2b(ar0[r] + sbias[16+ml]);
      vrt[ml][tok] = f2b(ar1[r] + sbias[32+ml]);
    }
    __syncthreads();
    // ---- l2 norm of q, k, k_ref rows ----
    if (tid < 192){
      int rr = tid & 63;
      bf16* row = (tid < 64) ? qs[rr] : (tid < 128) ? ks[rr] : krs[rr];
      float s = 0.f;
      #pragma unroll
      for (int d = 0; d < 16; ++d){ float v = b2f(row[d]); s += v*v; }
      float inv = 1.f / fmaxf(sqrtf(s), 1e-12f);
      #pragma unroll
      for (int d = 0; d < 16; ++d) row[d] = f2b(b2f(row[d]) * inv);
    }
    __syncthreads();

    float ls = expf(fminf(b2f(lsc[h]), 4.605170185988091f));
    float gv = b2f(gat[h]);
    float g = 1.f / (1.f + expf(-gv));

    // ---- S = Qn.KnT (and Qn.KrnT): 4 n-tiles per wave ----
    float4v s1[4], s2[4];
    {
      short8v qf = *(const short8v*)&qs[wv*16 + ml][quad*8];
      #pragma unroll
      for (int nt = 0; nt < 4; ++nt){
        short8v kf  = *(const short8v*)&ks[nt*16 + ml][quad*8];
        short8v krf = *(const short8v*)&krs[nt*16 + ml][quad*8];
        float4v z = {0,0,0,0};
        s1[nt] = __builtin_amdgcn_mfma_f32_16x16x32_bf16(qf, kf,  z, 0,0,0);
        s2[nt] = __builtin_amdgcn_mfma_f32_16x16x32_bf16(qf, krf, z, 0,0,0);
      }
    }
    // ---- epilogue: scale, rpb, mask, softmax (C-layout rows) ----
    float sv1[4][4], sv2[4][4];
    #pragma unroll
    for (int r = 0; r < 4; ++r){
      int ti = wv*16 + quad*4 + r;
      int iy = ti >> 3, ix = ti & 7;
      int regi = ((wh < 31) ? 0 : (iy < 4 ? 1 : 2))*3 + ((ww < 31) ? 0 : (ix < 4 ? 1 : 2));
      #pragma unroll
      for (int nt = 0; nt < 4; ++nt){
        int tj = nt*16 + ml;
        int jy = tj >> 3, jx = tj & 7;
        int regj = ((wh < 31) ? 0 : (jy < 4 ? 1 : 2))*3 + ((ww < 31) ? 0 : (jx < 4 ? 1 : 2));
        float rp = rpbs[(iy - jy + 7)*15 + (ix - jx + 7)];
        float msk = (regi != regj) ? -100.f : 0.f;
        sv1[nt][r] = s1[nt][r]*ls + rp + msk;
        sv2[nt][r] = s2[nt][r]*ls + rp + msk;
      }
    }
    float f1[4], f2[4];
    #pragma unroll
    for (int r = 0; r < 4; ++r){
      float mx1 = -1e30f, mx2 = -1e30f;
      #pragma unroll
      for (int nt = 0; nt < 4; ++nt){ mx1 = fmaxf(mx1, sv1[nt][r]); mx2 = fmaxf(mx2, sv2[nt][r]); }
      #pragma unroll
      for (int m = 1; m < 16; m <<= 1){ mx1 = fmaxf(mx1, __shfl_xor(mx1, m, 64)); mx2 = fmaxf(mx2, __shfl_xor(mx2, m, 64)); }
      float sm1 = 0.f, sm2 = 0.f;
      #pragma unroll
      for (int nt = 0; nt < 4; ++nt){
        sv1[nt][r] = expf(sv1[nt][r] - mx1); sm1 += sv1[nt][r];
        sv2[nt][r] = expf(sv2[nt][r] - mx2); sm2 += sv2[nt][r];
      }
      #pragma unroll
      for (int m = 1; m < 16; m <<= 1){ sm1 += __shfl_xor(sm1, m, 64); sm2 += __shfl_xor(sm2, m, 64); }
      f1[r] = (1.f - g) / sm1;
      f2[r] = g / sm2;
    }

    // ---- PV path 1 (ps rows are wave-private: no barriers needed) ----
    #pragma unroll
    for (int r = 0; r < 4; ++r){
      int ti = wv*16 + quad*4 + r;
      #pragma unroll
      for (int nt = 0; nt < 4; ++nt) ps[ti][nt*16 + ml] = f2b(sv1[nt][r] * f1[r]);
    }
    float4v po = {0,0,0,0};
    #pragma unroll
    for (int kt = 0; kt < 2; ++kt){
      short8v pa = *(const short8v*)&ps[wv*16 + ml][kt*32 + quad*8];
      short8v vb = *(const short8v*)&vt[ml][kt*32 + quad*8];
      po = __builtin_amdgcn_mfma_f32_16x16x32_bf16(pa, vb, po, 0,0,0);
    }
    // ---- PV path 2 (reuse ps) ----
    #pragma unroll
    for (int r = 0; r < 4; ++r){
      int ti = wv*16 + quad*4 + r;
      #pragma unroll
      for (int nt = 0; nt < 4; ++nt) ps[ti][nt*16 + ml] = f2b(sv2[nt][r] * f2[r]);
    }
    #pragma unroll
    for (int kt = 0; kt < 2; ++kt){
      short8v pa = *(const short8v*)&ps[wv*16 + ml][kt*32 + quad*8];
      short8v vb = *(const short8v*)&vrt[ml][kt*32 + quad*8];
      po = __builtin_amdgcn_mfma_f32_16x16x32_bf16(pa, vb, po, 0,0,0);
    }
    // ---- write out (shifted coords) ----
    #pragma unroll
    for (int r = 0; r < 4; ++r){
      int tok = wv*16 + quad*4 + r;
      int hs = wh*8 + (tok >> 3), wsp = ww*8 + (tok & 7);
      img[(((long)b*HH + hs)*WWID + wsp)*CC + h*HDIM + ml] = f2b(po[r]);
    }
  }
}

// ---------------- MFMA implicit-GEMM 3x3 conv (NHWC, pad 1) -----------------
template<int CIN, int COUT, int MODE>
__global__ __launch_bounds__(256) void convmfma_kernel(const bf16* __restrict__ src,
                                                       const bf16* __restrict__ wt,
                                                       const bf16* __restrict__ bias,
                                                       const bf16* __restrict__ base,
                                                       bf16* __restrict__ dst)
{
  constexpr int NB = 96;
  constexpr int AP = CIN + 8;
  constexpr int C8 = CIN / 8;
  __shared__ __align__(16) bf16 act[100*AP];
  __shared__ __align__(16) bf16 wsm[NB*AP];

  int tid = threadIdx.x;
  int z = blockIdx.z;
  int bb = (COUT == NB) ? z : (z >> 1);
  int n0 = (COUT == NB) ? 0 : ((z & 1) * NB);
  int tx0 = blockIdx.x * 8, ty0 = blockIdx.y * 8;

  for (int idx = tid; idx < 100*C8; idx += 256){
    int pp = idx / C8, c8 = idx - pp*C8;
    int iy = pp / 10, ix = pp - iy*10;
    int gy = ty0 + iy - 1, gx = tx0 + ix - 1;
    uint4 v = make_uint4(0,0,0,0);
    if ((unsigned)gy < (unsigned)HH && (unsigned)gx < (unsigned)WWID)
      v = *(const uint4*)&src[(((long)bb*HH + gy)*WWID + gx)*CIN + c8*8];
    *(uint4*)&act[pp*AP + c8*8] = v;
  }

  int wv = tid >> 6, lane = tid & 63;
  int wm = wv >> 1, wn = wv & 1;
  int ml = lane & 15, quad = lane >> 4;

  float4v acc[2][3];
  #pragma unroll
  for (int nt = 0; nt < 3; ++nt){
    float bv = b2f(bias[n0 + wn*48 + nt*16 + ml]);
    #pragma unroll
    for (int mt = 0; mt < 2; ++mt)
      acc[mt][nt] = (float4v){bv, bv, bv, bv};
  }

  int pl0 = wm*32 + ml, pl1 = pl0 + 16;
  int py0 = pl0 >> 3, px0 = pl0 & 7;
  int py1 = pl1 >> 3, px1 = pl1 & 7;

  for (int tap = 0; tap < 9; ++tap){
    __syncthreads();
    const bf16* wsrc = wt + ((long)tap*COUT + n0)*CIN;
    for (int idx = tid; idx < NB*C8; idx += 256){
      int rr = idx / C8, c8 = idx - rr*C8;
      *(uint4*)&wsm[rr*AP + c8*8] = *(const uint4*)&wsrc[rr*CIN + c8*8];
    }
    __syncthreads();
    int dy = tap / 3, dx = tap - dy*3;
    int ar0 = ((py0+dy)*10 + px0 + dx)*AP;
    int ar1 = ((py1+dy)*10 + px1 + dx)*AP;
    int br0 = (wn*48 + ml)*AP, br1 = br0 + 16*AP, br2 = br0 + 32*AP;
    #pragma unroll
    for (int kc = 0; kc < CIN/32; ++kc){
      int ko = kc*32 + quad*8;
      short8v a0 = *(const short8v*)&act[ar0 + ko];
      short8v a1 = *(const short8v*)&act[ar1 + ko];
      short8v b0 = *(const short8v*)&wsm[br0 + ko];
      short8v b1 = *(const short8v*)&wsm[br1 + ko];
      short8v b2 = *(const short8v*)&wsm[br2 + ko];
      acc[0][0] = __builtin_amdgcn_mfma_f32_16x16x32_bf16(a0, b0, acc[0][0], 0, 0, 0);
      acc[0][1] = __builtin_amdgcn_mfma_f32_16x16x32_bf16(a0, b1, acc[0][1], 0, 0, 0);
      acc[0][2] = __builtin_amdgcn_mfma_f32_16x16x32_bf16(a0, b2, acc[0][2], 0, 0, 0);
      acc[1][0] = __builtin_amdgcn_mfma_f32_16x16x32_bf16(a1, b0, acc[1][0], 0, 0, 0);
      acc[1][1] = __builtin_amdgcn_mfma_f32_16x16x32_bf16(a1, b1, acc[1][1], 0, 0, 0);
      acc[1][2] = __builtin_amdgcn_mfma_f32_16x16x32_bf16(a1, b2, acc[1][2], 0, 0, 0);
    }
  }

  #pragma unroll
  for (int mt = 0; mt < 2; ++mt){
    #pragma unroll
    for (int r = 0; r < 4; ++r){
      int pl = wm*32 + mt*16 + quad*4 + r;
      int py = pl >> 3, px = pl & 7;
      long ob = (((long)bb*HH + ty0+py)*WWID + tx0+px)*COUT + n0 + wn*48 + ml;
      #pragma unroll
      for (int nt = 0; nt < 3; ++nt){
        float v = acc[mt][nt][r];
        long o = ob + nt*16;
        if (MODE == 0)      dst[o] = f2b(fmaxf(v, 0.f));
        else if (MODE == 1) dst[o] = f2b(b2f(base[o]) + v);
        else                dst[o] = f2b(0.5f * v * (1.f + erff(v * 0.7071067811865476f)));
      }
    }
  }
}

// ---------------- proj (96x96) + roll-back(+4,+4) + shortcut -> bf16 xmid ---
#define PPITCH (CC+8)
__global__ __launch_bounds__(256) void proj_kernel(const bf16* __restrict__ img, const bf16* __restrict__ pw,
                                                   const bf16* __restrict__ pb, const bf16* __restrict__ xorig,
                                                   bf16* __restrict__ xmid)
{
  __shared__ __align__(16) bf16 rows[64][PPITCH];
  __shared__ __align__(16) bf16 wsm[CC][PPITCH];
  long pix0 = (long)blockIdx.x * 64;
  int tid = threadIdx.x;
  for (int idx = tid; idx < 64*CC; idx += 256){
    int pp = idx / CC, c = idx - pp*CC;
    long pix = pix0 + pp;
    int b = (int)(pix >> 16); int hw = (int)(pix & 65535);
    int h = hw >> 8, wc = hw & 255;
    int sh = (h - SHIFTV) & 255, sw = (wc - SHIFTV) & 255;
    rows[pp][c] = img[(((long)b*HH + sh)*WWID + sw)*CC + c];
  }
  for (int idx = tid; idx < CC*CC; idx += 256){
    int rr = idx / CC, c = idx - rr*CC;
    wsm[rr][c] = pw[idx];
  }
  __syncthreads();
  int ty = tid >> 4, tx = tid & 15;
  int r0 = ty*4;
  float acc[4][6];
  #pragma unroll
  for (int j = 0; j < 6; ++j){
    float bv = b2f(pb[tx + 16*j]);
    #pragma unroll
    for (int i = 0; i < 4; ++i) acc[i][j] = bv;
  }
  for (int kk = 0; kk < 12; ++kk){
    uint4 a0 = ((const uint4*)rows[r0+0])[kk];
    uint4 a1 = ((const uint4*)rows[r0+1])[kk];
    uint4 a2 = ((const uint4*)rows[r0+2])[kk];
    uint4 a3 = ((const uint4*)rows[r0+3])[kk];
    #pragma unroll
    for (int j = 0; j < 6; ++j){
      uint4 wv = ((const uint4*)wsm[tx + 16*j])[kk];
      acc[0][j] = dot8(a0, wv, acc[0][j]);
      acc[1][j] = dot8(a1, wv, acc[1][j]);
      acc[2][j] = dot8(a2, wv, acc[2][j]);
      acc[3][j] = dot8(a3, wv, acc[3][j]);
    }
  }
  #pragma unroll
  for (int i = 0; i < 4; ++i){
    long pix = pix0 + r0 + i;
    #pragma unroll
    for (int j = 0; j < 6; ++j){
      long oi = pix*CC + tx + 16*j;
      xmid[oi] = f2b(b2f(xorig[oi]) + acc[i][j]);
    }
  }
}

// ---------------- fc1: 96->192 + exact GELU ---------------------------------
__global__ __launch_bounds__(256) void fc1_kernel(const bf16* __restrict__ src, const bf16* __restrict__ w,
                                                  const bf16* __restrict__ bias, bf16* __restrict__ dst)
{
  __shared__ __align__(16) bf16 rows[64][PPITCH];
  __shared__ __align__(16) bf16 wsm[HID][PPITCH];
  long pix0 = (long)blockIdx.x * 64;
  int tid = threadIdx.x;
  for (int idx = tid; idx < 64*CC; idx += 256){
    int pp = idx / CC, c = idx - pp*CC;
    rows[pp][c] = src[(pix0 + pp)*CC + c];
  }
  for (int idx = tid; idx < HID*CC; idx += 256){
    int rr = idx / CC, c = idx - rr*CC;
    wsm[rr][c] = w[idx];
  }
  __syncthreads();
  int ty = tid >> 4, tx = tid & 15;
  int r0 = ty*4;
  float acc[4][12];
  #pragma unroll
  for (int j = 0; j < 12; ++j){
    float bv = b2f(bias[tx + 16*j]);
    #pragma unroll
    for (int i = 0; i < 4; ++i) acc[i][j] = bv;
  }
  for (int kk = 0; kk < 12; ++kk){
    uint4 a0 = ((const uint4*)rows[r0+0])[kk];
    uint4 a1 = ((const uint4*)rows[r0+1])[kk];
    uint4 a2 = ((const uint4*)rows[r0+2])[kk];
    uint4 a3 = ((const uint4*)rows[r0+3])[kk];
    #pragma unroll
    for (int j = 0; j < 12; ++j){
      uint4 wv = ((const uint4*)wsm[tx + 16*j])[kk];
      acc[0][j] = dot8(a0, wv, acc[0][j]);
      acc[1][j] = dot8(a1, wv, acc[1][j]);
      acc[2][j] = dot8(a2, wv, acc[2][j]);
      acc[3][j] = dot8(a3, wv, acc[3][j]);
    }
  }
  #pragma unroll
  for (int i = 0; i < 4; ++i){
    long pix = pix0 + r0 + i;
    #pragma unroll
    for (int j = 0; j < 12; ++j){
      float v = acc[i][j];
      dst[pix*HID + tx + 16*j] = f2b(0.5f * v * (1.f + erff(v * 0.7071067811865476f)));
    }
  }
}

// ---------------- fc2: 192->96 + bf16 xmid residual -> out (flag dtype) -----
#define FPITCH (HID+8)
__global__ __launch_bounds__(256) void fc2_kernel(const bf16* __restrict__ src, const bf16* __restrict__ w,
                                                  const bf16* __restrict__ bias, const bf16* __restrict__ xmid,
                                                  void* __restrict__ outv, const int* __restrict__ flag)
{
  __shared__ __align__(16) bf16 rows[64][FPITCH];
  __shared__ __align__(16) bf16 wsm[CC][FPITCH];
  long pix0 = (long)blockIdx.x * 64;
  int tid = threadIdx.x;
  for (int idx = tid; idx < 64*HID; idx += 256){
    int pp = idx / HID, c = idx - pp*HID;
    rows[pp][c] = src[(pix0 + pp)*HID + c];
  }
  for (int idx = tid; idx < CC*HID; idx += 256){
    int rr = idx / HID, c = idx - rr*HID;
    wsm[rr][c] = w[idx];
  }
  __syncthreads();
  int ty = tid >> 4, tx = tid & 15;
  int r0 = ty*4;
  float acc[4][6];
  #pragma unroll
  for (int j = 0; j < 6; ++j){
    float bv = b2f(bias[tx + 16*j]);
    #pragma unroll
    for (int i = 0; i < 4; ++i) acc[i][j] = bv;
  }
  for (int kk = 0; kk < 24; ++kk){
    uint4 a0 = ((const uint4*)rows[r0+0])[kk];
    uint4 a1 = ((const uint4*)rows[r0+1])[kk];
    uint4 a2 = ((const uint4*)rows[r0+2])[kk];
    uint4 a3 = ((const uint4*)rows[r0+3])[kk];
    #pragma unroll
    for (int j = 0; j < 6; ++j){
      uint4 wv = ((const uint4*)wsm[tx + 16*j])[kk];
      acc[0][j] = dot8(a0, wv, acc[0][j]);
      acc[1][j] = dot8(a1, wv, acc[1][j]);
      acc[2][j] = dot8(a2, wv, acc[2][j]);
      acc[3][j] = dot8(a3, wv, acc[3][j]);
    }
  }
  int f = *flag;
  #pragma unroll
  for (int i = 0; i < 4; ++i){
    long pix = pix0 + r0 + i;
    #pragma unroll
    for (int j = 0; j < 6; ++j){
      long oi = pix*CC + tx + 16*j;
      float v = b2f(xmid[oi]) + acc[i][j];
      if (f) ((float*)outv)[oi] = v;
      else   ((bf16*)outv)[oi] = f2b(v);
    }
  }
}

extern "C" void kernel_launch(void* const* d_in, const int* in_sizes, int n_in,
                              void* d_out, int out_size, void* d_ws, size_t ws_size,
                              hipStream_t stream)
{
  long cum[22]; cum[0] = 0;
  for (int i = 0; i < 21; ++i) cum[i+1] = cum[i] + in_sizes[i];
  long total = cum[21];

  CvtArgs a;
  for (int i = 0; i < 21; ++i) a.src[i] = d_in[i];
  for (int i = 0; i < 22; ++i) a.cum[i] = cum[i];

  char* ws = (char*)d_ws;
  int*  flag   = (int*)ws;
  bf16* packed = (bf16*)(ws + 1048576);           // [1MiB, ~50.4MiB)

  detect_kernel<<<1, 256, 0, stream>>>((const unsigned*)d_in[0], flag);
  cvt_kernel<<<(int)((total + 255) / 256), 256, 0, stream>>>(a, flag, packed, total);

  #define PP(i) (packed + cum[i])
  const bf16* xc    = PP(0);
  const bf16* rc    = PP(1);
  const bf16* n1g   = PP(2);
  const bf16* n1b   = PP(3);
  const bf16* qkv_w = PP(4);
  const bf16* qkv_b = PP(5);
  const bf16* lsc   = PP(6);
  const bf16* gat   = PP(7);
  const bf16* rpbt  = PP(8);
  const bf16* tw    = PP(9);
  const bf16* tb    = PP(10);
  const bf16* pw    = PP(11);
  const bf16* pb    = PP(12);
  const bf16* n2g   = PP(13);
  const bf16* n2b   = PP(14);
  const bf16* f1w   = PP(15);
  const bf16* f1b   = PP(16);
  const bf16* cmw   = PP(17);
  const bf16* cmb   = PP(18);
  const bf16* f2w   = PP(19);
  const bf16* f2bp  = PP(20);

  // --- workspace layout (peak ~124 MiB) -------------------------------------
  bf16* wtc  = (bf16*)(ws + 52860928);            // trunk wT  [36][96][96]
  bf16* wtm  = (bf16*)(ws + 53524480);            // convm wT  [9][192][192]
  bf16* xn   = (bf16*)(ws + 54525952);            // 52 MiB
  bf16* rn   = (bf16*)(ws + 79691776);            // 76 MiB
  bf16* img  = (bf16*)(ws + 104857600);           // 100 MiB
  bf16* rtr  = xn;
  bf16* xmid = xn;
  bf16* ln2o = rn;
  bf16* h1   = (bf16*)(ws + 1048576);
  bf16* hc   = rn;

  wtrans_kernel<<<1296, 256, 0, stream>>>(tw, wtc, 96, 96, 331776);
  wtrans_kernel<<<1296, 256, 0, stream>>>(cmw, wtm, 192, 192, 331776);

  ln1_kernel<<<65536, 256, 0, stream>>>(xc, rc, n1g, n1b, xn, rn);
  attn_kernel<<<2048, 256, 0, stream>>>(xn, rn, qkv_w, qkv_b, lsc, gat, rpbt, img);

  convmfma_kernel<96,96,0><<<dim3(32,32,2), 256, 0, stream>>>(img, wtc + 0*82944, tb + 0,   nullptr, rtr);
  convmfma_kernel<96,96,1><<<dim3(32,32,2), 256, 0, stream>>>(rtr, wtc + 1*82944, tb + 96,  img,     img);
  convmfma_kernel<96,96,0><<<dim3(32,32,2), 256, 0, stream>>>(img, wtc + 2*82944, tb + 192, nullptr, rtr);
  convmfma_kernel<96,96,1><<<dim3(32,32,2), 256, 0, stream>>>(rtr, wtc + 3*82944, tb + 288, img,     img);

  proj_kernel<<<2048, 256, 0, stream>>>(img, pw, pb, xc, xmid);
  ln2_kernel<<<32768, 256, 0, stream>>>(xmid, n2g, n2b, ln2o);
  fc1_kernel<<<2048, 256, 0, stream>>>(ln2o, f1w, f1b, h1);
  convmfma_kernel<192,192,2><<<dim3(32,32,4), 256, 0, stream>>>(h1, wtm, cmb, nullptr, hc);
  fc2_kernel<<<2048, 256, 0, stream>>>(hc, f2w, f2bp, xmid, d_out, flag);
}